// Round 7
// baseline (23176.207 us; speedup 1.0000x reference)
//
#include <hip/hip_runtime.h>
#include <hip/hip_bf16.h>

typedef long long i64;

// ---- output element offsets (FLOAT32 elements — d_out is float*) ----
static constexpr i64 OUT_POLICY = 0;
static constexpr i64 OUT_VALUE  = 46336;
static constexpr i64 OUT_ZE0    = 46464;
static constexpr i64 OUT_ZE1    = 1525120;
static constexpr i64 OUT_ZE2    = 1590656;
static constexpr i64 OUT_ZQ0    = 1656192;
static constexpr i64 OUT_ZQ1    = 3134848;
static constexpr i64 OUT_ZQ2    = 3200384;
static constexpr i64 OUT_K0     = 3265920;
static constexpr i64 OUT_K1     = 3312128;
static constexpr i64 OUT_K2     = 3313152;
static constexpr i64 OUT_ZQL0   = 3314176;
static constexpr i64 OUT_ZQL1   = 4792832;
static constexpr i64 OUT_ZQL2   = 4858368;
static constexpr i64 OUT_EM0    = 4923904;
static constexpr i64 OUT_EM1    = 6402560;
static constexpr i64 OUT_EM2    = 6468096;
static constexpr i64 OUT_TOTAL  = 6533632;

// =============== conv 3x3 SAME, NCHW, f32, no bias (BN cancels it) ===============
// 32 output channels per block (named scalar accumulators), CHUNK input channels
// staged in LDS per step, global->reg prefetch of next chunk overlapped with compute.
template<int CIN, int CHUNK>
__global__ __launch_bounds__(384)
void conv3x3_k(const float* __restrict__ in, const float* __restrict__ w,
               float* __restrict__ out, int cout)
{
    constexpr int NS    = CHUNK * 441;
    constexpr int NITER = (NS + 383) / 384;
    __shared__ float tile[NS];
    const int n   = blockIdx.x;
    const int co0 = blockIdx.y * 32;
    const int tid = threadIdx.x;
    const bool act = tid < 361;
    const int y = tid / 19, x = tid % 19;
    const int base = y * 21 + x;

    float v[NITER];

#define LOAD_CHUNK(CI0)                                                        \
    _Pragma("unroll")                                                          \
    for (int i = 0; i < NITER; i++) {                                          \
        int idx = tid + i * 384;                                               \
        if (idx < NS) {                                                        \
            int p = idx / 441, r = idx - p * 441;                              \
            int yy = r / 21, xx = r - yy * 21;                                 \
            int iy = yy - 1, ix = xx - 1;                                      \
            float val = 0.f;                                                   \
            if (iy >= 0 && iy < 19 && ix >= 0 && ix < 19)                      \
                val = in[((i64)n * CIN + (CI0) + p) * 361 + iy * 19 + ix];     \
            v[i] = val;                                                        \
        }                                                                      \
    }

    float a0=0.f,a1=0.f,a2=0.f,a3=0.f,a4=0.f,a5=0.f,a6=0.f,a7=0.f;
    float a8=0.f,a9=0.f,a10=0.f,a11=0.f,a12=0.f,a13=0.f,a14=0.f,a15=0.f;
    float a16=0.f,a17=0.f,a18=0.f,a19=0.f,a20=0.f,a21=0.f,a22=0.f,a23=0.f;
    float a24=0.f,a25=0.f,a26=0.f,a27=0.f,a28=0.f,a29=0.f,a30=0.f,a31=0.f;

    LOAD_CHUNK(0)

    for (int ci0 = 0; ci0 < CIN; ci0 += CHUNK) {
        __syncthreads();               // previous compute done; LDS reusable
#pragma unroll
        for (int i = 0; i < NITER; i++) {
            int idx = tid + i * 384;
            if (idx < NS) tile[idx] = v[i];
        }
        __syncthreads();               // LDS ready
        if (ci0 + CHUNK < CIN) { LOAD_CHUNK(ci0 + CHUNK) }   // prefetch (overlaps compute)

        if (act) {
#pragma unroll 1
            for (int p = 0; p < CHUNK; p++) {
                const float* tp = &tile[p * 441 + base];
                float t0 = tp[0],  t1 = tp[1],  t2 = tp[2];
                float t3 = tp[21], t4 = tp[22], t5 = tp[23];
                float t6 = tp[42], t7 = tp[43], t8 = tp[44];
                const float* wp = w + ((i64)co0 * CIN + ci0 + p) * 9;
#define DO_CO(A, I) { const float* wq = wp + (i64)(I) * CIN * 9;                         \
                A = fmaf(t0, wq[0], A); A = fmaf(t1, wq[1], A); A = fmaf(t2, wq[2], A);  \
                A = fmaf(t3, wq[3], A); A = fmaf(t4, wq[4], A); A = fmaf(t5, wq[5], A);  \
                A = fmaf(t6, wq[6], A); A = fmaf(t7, wq[7], A); A = fmaf(t8, wq[8], A); }
                DO_CO(a0, 0)  DO_CO(a1, 1)  DO_CO(a2, 2)  DO_CO(a3, 3)
                DO_CO(a4, 4)  DO_CO(a5, 5)  DO_CO(a6, 6)  DO_CO(a7, 7)
                DO_CO(a8, 8)  DO_CO(a9, 9)  DO_CO(a10,10) DO_CO(a11,11)
                DO_CO(a12,12) DO_CO(a13,13) DO_CO(a14,14) DO_CO(a15,15)
                DO_CO(a16,16) DO_CO(a17,17) DO_CO(a18,18) DO_CO(a19,19)
                DO_CO(a20,20) DO_CO(a21,21) DO_CO(a22,22) DO_CO(a23,23)
                DO_CO(a24,24) DO_CO(a25,25) DO_CO(a26,26) DO_CO(a27,27)
                DO_CO(a28,28) DO_CO(a29,29) DO_CO(a30,30) DO_CO(a31,31)
#undef DO_CO
            }
        }
    }
#undef LOAD_CHUNK
    if (act) {
        float* op = out + ((i64)n * cout + co0) * 361 + tid;
        op[0*361]=a0;   op[1*361]=a1;   op[2*361]=a2;   op[3*361]=a3;
        op[4*361]=a4;   op[5*361]=a5;   op[6*361]=a6;   op[7*361]=a7;
        op[8*361]=a8;   op[9*361]=a9;   op[10*361]=a10; op[11*361]=a11;
        op[12*361]=a12; op[13*361]=a13; op[14*361]=a14; op[15*361]=a15;
        op[16*361]=a16; op[17*361]=a17; op[18*361]=a18; op[19*361]=a19;
        op[20*361]=a20; op[21*361]=a21; op[22*361]=a22; op[23*361]=a23;
        op[24*361]=a24; op[25*361]=a25; op[26*361]=a26; op[27*361]=a27;
        op[28*361]=a28; op[29*361]=a29; op[30*361]=a30; op[31*361]=a31;
    }
}

// =============== BN batch-stats -> scale/shift ===============
__global__ __launch_bounds__(256)
void bnstats_k(const float* __restrict__ x, const float* __restrict__ g,
               const float* __restrict__ b, float* __restrict__ scale,
               float* __restrict__ shift, int C)
{
    const int c = blockIdx.x;
    float s = 0.f, s2 = 0.f;
    for (int n = 0; n < 128; n++) {
        const float* p = x + ((i64)n * C + c) * 361;
        for (int i = threadIdx.x; i < 361; i += 256) {
            float v = p[i]; s += v; s2 += v * v;
        }
    }
    __shared__ float rs[4], rq[4];
    for (int o = 32; o > 0; o >>= 1) { s += __shfl_down(s, o); s2 += __shfl_down(s2, o); }
    int lane = threadIdx.x & 63, wid = threadIdx.x >> 6;
    if (lane == 0) { rs[wid] = s; rq[wid] = s2; }
    __syncthreads();
    if (threadIdx.x == 0) {
        float S = rs[0] + rs[1] + rs[2] + rs[3];
        float Q = rq[0] + rq[1] + rq[2] + rq[3];
        const float inv = 1.f / 46208.f;
        float m  = S * inv;
        float var = Q * inv - m * m;
        float sc = g[c] * rsqrtf(var + 1e-5f);
        scale[c] = sc;
        shift[c] = b[c] - m * sc;
    }
}

// =============== BN apply variants (ws-only) ===============
__global__ void bn_relu_k(float* __restrict__ x, const float* __restrict__ scale,
                          const float* __restrict__ shift, int C, int total)
{
    for (int i = blockIdx.x * blockDim.x + threadIdx.x; i < total; i += gridDim.x * blockDim.x) {
        int c = (i / 361) % C;
        float v = fmaf(x[i], scale[c], shift[c]);
        x[i] = v > 0.f ? v : 0.f;
    }
}

__global__ void bn_add_relu_slice_k(float* __restrict__ xa, const float* __restrict__ xc,
                                    const float* __restrict__ scale, const float* __restrict__ shift,
                                    int cbase, int total)
{
    for (int i = blockIdx.x * blockDim.x + threadIdx.x; i < total; i += gridDim.x * blockDim.x) {
        int s = i % 361;
        int t = i / 361;
        int ch = t % 64;
        int n = t / 64;
        i64 ai = ((i64)n * 256 + cbase + ch) * 361 + s;
        float v = xa[ai] + fmaf(xc[i], scale[ch], shift[ch]);
        xa[ai] = v > 0.f ? v : 0.f;
    }
}

__global__ void bn_tanh_ws_k(const float* __restrict__ x, const float* __restrict__ scale,
                             const float* __restrict__ shift, float* __restrict__ zf, int total)
{
    for (int i = blockIdx.x * blockDim.x + threadIdx.x; i < total; i += gridDim.x * blockDim.x) {
        int c = (i / 361) & 31;
        zf[i] = tanhf(fmaf(x[i], scale[c], shift[c]));
    }
}

// =============== codebook prep ===============
__global__ void prep_k(const float* __restrict__ E0, const float* __restrict__ E1,
                       const float* __restrict__ E2,
                       float* __restrict__ ee0, float* __restrict__ ee1, float* __restrict__ ee2,
                       float* __restrict__ cm0, float* __restrict__ cm1, float* __restrict__ cm2)
{
    int t = threadIdx.x;
    if (blockIdx.x == 0) {
        float s = 0.f; const float* e = E0 + (i64)t * 32;
        for (int d = 0; d < 32; d++) s += e[d] * e[d];
        ee0[t] = s;
    } else if (blockIdx.x == 1) {
        float s = 0.f; const float* e = E1 + (i64)t * 64;
        for (int d = 0; d < 64; d++) s += e[d] * e[d];
        ee1[t] = s;
    } else if (blockIdx.x == 2) {
        float s = 0.f; const float* e = E2 + (i64)t * 64;
        for (int d = 0; d < 64; d++) s += e[d] * e[d];
        ee2[t] = s;
    } else {
        if (t < 32) {
            float s = 0.f; for (int k = 0; k < 512; k++) s += E0[k * 32 + t];
            cm0[t] = s * (1.f / 512.f);
        } else if (t >= 64 && t < 128) {
            int d = t - 64; float s = 0.f; for (int k = 0; k < 512; k++) s += E1[k * 64 + d];
            cm1[d] = s * (1.f / 512.f);
        } else if (t >= 128 && t < 192) {
            int d = t - 128; float s = 0.f; for (int k = 0; k < 512; k++) s += E2[k * 64 + d];
            cm2[d] = s * (1.f / 512.f);
        }
    }
}

// =============== VQ kernels (32 KB LDS, multi-pass staging) ===============
__global__ __launch_bounds__(256)
void vq0_k(const float* __restrict__ z, const float* __restrict__ E,
           const float* __restrict__ ee, float* __restrict__ zqf, int* __restrict__ ki)
{
    __shared__ float Es[256 * 32];
    int row = blockIdx.x * 256 + threadIdx.x;
    const bool live = row < 46208;
    const float* zp = z + (i64)(live ? row : 0) * 32;
    float zv[32]; float zz = 0.f;
#pragma unroll
    for (int d = 0; d < 32; d++) { float v = zp[d]; zv[d] = v; zz += v * v; }
    float best = 3.4e38f; int bk = 0;
    for (int h = 0; h < 2; h++) {
        __syncthreads();
        for (int i = threadIdx.x; i < 256 * 32; i += 256) Es[i] = E[h * 8192 + i];
        __syncthreads();
        for (int k = 0; k < 256; k++) {
            const float* e = Es + k * 32;
            float dot = 0.f;
#pragma unroll
            for (int d = 0; d < 32; d++) dot = fmaf(zv[d], e[d], dot);
            float dist = (zz + ee[h * 256 + k]) - 2.f * dot;
            if (dist < best) { best = dist; bk = h * 256 + k; }
        }
    }
    if (live) {
        ki[row] = bk;
        const float* eb = E + (i64)bk * 32;
#pragma unroll
        for (int d = 0; d < 32; d++) zqf[(i64)row * 32 + d] = eb[d];
    }
}

__global__ __launch_bounds__(256)
void vq64_k(const float* __restrict__ z, const float* __restrict__ E,
            const float* __restrict__ ee, float* __restrict__ zqf, int* __restrict__ ki)
{
    __shared__ float Es[128 * 64];
    int row = blockIdx.x * 256 + threadIdx.x;
    const float* zp = z + (i64)row * 64;
    float zv[64]; float zz = 0.f;
#pragma unroll
    for (int d = 0; d < 64; d++) { float v = zp[d]; zv[d] = v; zz += v * v; }
    float best = 3.4e38f; int bk = 0;
    for (int h = 0; h < 4; h++) {
        __syncthreads();
        for (int i = threadIdx.x; i < 128 * 64; i += 256) Es[i] = E[(i64)h * 8192 + i];
        __syncthreads();
        for (int k = 0; k < 128; k++) {
            const float* e = Es + k * 64;
            float dot = 0.f;
#pragma unroll
            for (int d = 0; d < 64; d++) dot = fmaf(zv[d], e[d], dot);
            float dist = (zz + ee[h * 128 + k]) - 2.f * dot;
            if (dist < best) { best = dist; bk = h * 128 + k; }
        }
    }
    ki[row] = bk;
    const float* eb = E + (i64)bk * 64;
#pragma unroll
    for (int d = 0; d < 64; d++) zqf[(i64)row * 64 + d] = eb[d];
}

// =============== split-K GEMM ===============
__global__ __launch_bounds__(256)
void gemm_part_k(const float* __restrict__ A, const float* __restrict__ W,
                 float* __restrict__ part, int K, int N, int kchunk)
{
    __shared__ float As[128][17];
    __shared__ float Ws[16][64];
    const int n0 = blockIdx.x * 64;
    const int ks = blockIdx.y;
    const int kb0  = ks * kchunk;
    const int kend = min(K, kb0 + kchunk);
    const int tid = threadIdx.x;
    const int tn = tid & 15, tm = tid >> 4;
    float acc[8][4];
#pragma unroll
    for (int i = 0; i < 8; i++)
#pragma unroll
        for (int j = 0; j < 4; j++) acc[i][j] = 0.f;

    for (int kb = kb0; kb < kend; kb += 16) {
        __syncthreads();
        for (int i = tid; i < 2048; i += 256) {
            int m = i >> 4, kk = i & 15;
            int k = kb + kk;
            As[m][kk] = (k < kend) ? A[(i64)m * K + k] : 0.f;
        }
        for (int i = tid; i < 1024; i += 256) {
            int kk = i >> 6, nl = i & 63;
            int k = kb + kk, n = n0 + nl;
            Ws[kk][nl] = (k < kend && n < N) ? W[(i64)k * N + n] : 0.f;
        }
        __syncthreads();
#pragma unroll
        for (int kk = 0; kk < 16; kk++) {
            float av[8], wv[4];
#pragma unroll
            for (int i = 0; i < 8; i++) av[i] = As[tm * 8 + i][kk];
#pragma unroll
            for (int j = 0; j < 4; j++) wv[j] = Ws[kk][tn * 4 + j];
#pragma unroll
            for (int i = 0; i < 8; i++)
#pragma unroll
                for (int j = 0; j < 4; j++) acc[i][j] = fmaf(av[i], wv[j], acc[i][j]);
        }
    }
#pragma unroll
    for (int i = 0; i < 8; i++) {
        int m = tm * 8 + i;
#pragma unroll
        for (int j = 0; j < 4; j++) {
            int n = n0 + tn * 4 + j;
            if (n < N) part[((i64)ks * 128 + m) * N + n] = acc[i][j];
        }
    }
}

__global__ void combine_k(const float* __restrict__ part, const float* __restrict__ bias,
                          float* __restrict__ of, int MN, int N, int ksplit, int act)
{
    for (int i = blockIdx.x * blockDim.x + threadIdx.x; i < MN; i += gridDim.x * blockDim.x) {
        float s = 0.f;
        for (int t = 0; t < ksplit; t++) s += part[(i64)t * MN + i];
        s += bias[i % N];
        if (act == 1) s = s > 0.f ? s : 0.f;
        else if (act == 2) s = tanhf(s);
        of[i] = s;
    }
}

__global__ void blend_k(const float* __restrict__ q, const float* __restrict__ d,
                        const float* __restrict__ hu, int col, float* __restrict__ o,
                        int per_b, int total)
{
    for (int i = blockIdx.x * blockDim.x + threadIdx.x; i < total; i += gridDim.x * blockDim.x) {
        float u = hu[(i / per_b) * 2 + col];
        o[i] = u * q[i] + (1.f - u) * d[i];
    }
}

__global__ __launch_bounds__(256)
void value_k(const float* __restrict__ x, const float* __restrict__ w,
             const float* __restrict__ b, float* __restrict__ valf)
{
    int m = blockIdx.x;
    float s = 0.f;
    const float* xp = x + (i64)m * 11552;
    for (int k = threadIdx.x; k < 11552; k += 256) s = fmaf(xp[k], w[k], s);
    for (int o = 32; o > 0; o >>= 1) s += __shfl_down(s, o);
    __shared__ float r[4];
    int lane = threadIdx.x & 63, wid = threadIdx.x >> 6;
    if (lane == 0) r[wid] = s;
    __syncthreads();
    if (threadIdx.x == 0)
        valf[m] = tanhf(r[0] + r[1] + r[2] + r[3] + b[0]);
}

// =============== emit phase (d_out is FLOAT32) ===============
__global__ void emit_f32_k(const float* __restrict__ src, float* __restrict__ out, i64 off, int n)
{
    for (int i = blockIdx.x * blockDim.x + threadIdx.x; i < n; i += gridDim.x * blockDim.x)
        out[off + i] = src[i];
}

__global__ void emit_k_k(const int* __restrict__ ki, float* __restrict__ out, i64 off, int n)
{
    for (int i = blockIdx.x * blockDim.x + threadIdx.x; i < n; i += gridDim.x * blockDim.x)
        out[off + i] = (float)ki[i];
}

__global__ void emit_em_k(const float* __restrict__ cm, float* __restrict__ out, i64 off,
                          int D, int SPL, int total)
{
    for (int i = blockIdx.x * blockDim.x + threadIdx.x; i < total; i += gridDim.x * blockDim.x) {
        int c = (i / SPL) % D;
        out[off + i] = cm[c];
    }
}

// =============== guard markers ===============
__global__ void marker_k(float* __restrict__ out, int code)
{
    if (threadIdx.x < 64) out[threadIdx.x] = 3000.f + 100.f * code;
}

__global__ void sentinel_k(float* __restrict__ out)
{
    if (threadIdx.x < 128) out[OUT_VALUE + threadIdx.x] = 2000.0f;
}

// ===================== host launch =====================
extern "C" void kernel_launch(void* const* d_in, const int* in_sizes, int n_in,
                              void* d_out, int out_size, void* d_ws, size_t ws_size,
                              hipStream_t stream)
{
    float* out = (float*)d_out;

    int bad = -1;
    if (out_size != (int)OUT_TOTAL) bad = 0;
    else if (n_in != 41) bad = 1;
    else if (in_sizes[0] != 128 * 18 * 361) bad = 2;
    else if (in_sizes[21] != 11552 * 256) bad = 3;
    if (bad >= 0) { marker_k<<<1, 64, 0, stream>>>(out, bad); return; }

    const float* obs   = (const float*)d_in[0];
    const float* hier  = (const float*)d_in[1];
    const float* c0w   = (const float*)d_in[2];
    const float* bn0g  = (const float*)d_in[4];
    const float* bn0b  = (const float*)d_in[5];
    const float* rb1w  = (const float*)d_in[6];
    const float* rbn1g = (const float*)d_in[8];
    const float* rbn1b = (const float*)d_in[9];
    const float* rb2w  = (const float*)d_in[10];
    const float* rbn2g = (const float*)d_in[12];
    const float* rbn2b = (const float*)d_in[13];
    const float* c2w   = (const float*)d_in[14];
    const float* bn2g  = (const float*)d_in[16];
    const float* bn2b  = (const float*)d_in[17];
    const float* E0    = (const float*)d_in[18];
    const float* E1    = (const float*)d_in[19];
    const float* E2    = (const float*)d_in[20];
    const float* fc1w  = (const float*)d_in[21]; const float* fc1b  = (const float*)d_in[22];
    const float* fc2w  = (const float*)d_in[23]; const float* fc2b  = (const float*)d_in[24];
    const float* h2fw  = (const float*)d_in[25]; const float* h2fb  = (const float*)d_in[26];
    const float* h2f2w = (const float*)d_in[27]; const float* h2f2b = (const float*)d_in[28];
    const float* h2f3w = (const float*)d_in[29]; const float* h2f3b = (const float*)d_in[30];
    const float* h2f4w = (const float*)d_in[31]; const float* h2f4b = (const float*)d_in[32];
    const float* h1f3w = (const float*)d_in[33]; const float* h1f3b = (const float*)d_in[34];
    const float* h1f4w = (const float*)d_in[35]; const float* h1f4b = (const float*)d_in[36];
    const float* polw  = (const float*)d_in[37]; const float* polb  = (const float*)d_in[38];
    const float* valw  = (const float*)d_in[39]; const float* valb  = (const float*)d_in[40];

    float* wsf = (float*)d_ws;

    const size_t NEED_BYTES = (size_t)27271168 * 4;
    if (ws_size < NEED_BYTES) {
        sentinel_k<<<1, 128, 0, stream>>>(out);
        return;
    }

    float* scale = wsf + 0;        float* shift = wsf + 256;
    float* ee0 = wsf + 512;        float* ee1 = wsf + 1024;   float* ee2 = wsf + 1536;
    float* cm0 = wsf + 2048;       float* cm1 = wsf + 2112;   float* cm2 = wsf + 2176;
    int*   k0i = (int*)(wsf + 4096);
    int*   k1i = (int*)(wsf + 50304);
    int*   k2i = (int*)(wsf + 51328);
    float* h1a  = wsf + 53248;
    float* ze1f = wsf + 86016;
    float* zq1f = wsf + 151552;
    float* h2a  = wsf + 217088;
    float* ze2f = wsf + 233472;
    float* zq2f = wsf + 299008;
    float* h2b  = wsf + 364544;
    float* decf = wsf + 380928;
    float* x1f  = wsf + 446464;
    float* h1b  = wsf + 512000;
    float* polf = wsf + 544768;
    float* valf = wsf + 591104;

    float* A    = wsf + 655360;
    float* B    = wsf + 12484608;
    float* C64  = wsf + 24313856;
    float* ze0f = A;
    float* zq0f = wsf + 655360 + 1572864;
    float* dec0 = wsf + 655360 + 3145728;
    float* xf   = wsf + 655360 + 4718592;
    float* part = B;

    const int TOT256 = 128 * 256 * 361;
    const int TOT32  = 128 * 32 * 361;
    const int TOT64  = 128 * 64 * 361;

    prep_k<<<4, 512, 0, stream>>>(E0, E1, E2, ee0, ee1, ee2, cm0, cm1, cm2);

    // ---- trunk ----
    conv3x3_k<18, 6><<<dim3(128, 8), 384, 0, stream>>>(obs, c0w, A, 256);
    bnstats_k<<<256, 256, 0, stream>>>(A, bn0g, bn0b, scale, shift, 256);
    bn_relu_k<<<1024, 256, 0, stream>>>(A, scale, shift, 256, TOT256);

    for (int i = 0; i < 3; i++) {
        conv3x3_k<256, 8><<<dim3(128, 8), 384, 0, stream>>>(A, rb1w + (i64)i * 589824, B, 256);
        bnstats_k<<<256, 256, 0, stream>>>(B, rbn1g + i * 256, rbn1b + i * 256, scale, shift, 256);
        bn_relu_k<<<1024, 256, 0, stream>>>(B, scale, shift, 256, TOT256);
        for (int c = 0; c < 4; c++) {
            conv3x3_k<256, 8><<<dim3(128, 2), 384, 0, stream>>>(
                B, rb2w + (i64)i * 589824 + (i64)c * 64 * 256 * 9, C64, 64);
            bnstats_k<<<64, 256, 0, stream>>>(C64, rbn2g + i * 256 + c * 64,
                                              rbn2b + i * 256 + c * 64, scale, shift, 64);
            bn_add_relu_slice_k<<<1024, 256, 0, stream>>>(A, C64, scale, shift, c * 64, TOT64);
        }
    }

    conv3x3_k<256, 8><<<dim3(128, 1), 384, 0, stream>>>(A, c2w, C64, 32);
    bnstats_k<<<32, 256, 0, stream>>>(C64, bn2g, bn2b, scale, shift, 32);
    bn_tanh_ws_k<<<1024, 256, 0, stream>>>(C64, scale, shift, ze0f, TOT32);

    vq0_k<<<181, 256, 0, stream>>>(ze0f, E0, ee0, zq0f, k0i);

    gemm_part_k<<<dim3(4, 32), 256, 0, stream>>>(ze0f, fc1w, part, 11552, 256, 361);
    combine_k<<<128, 256, 0, stream>>>(part, fc1b, h1a, 128 * 256, 256, 32, 1);
    gemm_part_k<<<dim3(8, 4), 256, 0, stream>>>(h1a, fc2w, part, 256, 512, 64);
    combine_k<<<256, 256, 0, stream>>>(part, fc2b, ze1f, 128 * 512, 512, 4, 2);
    vq64_k<<<4, 256, 0, stream>>>(ze1f, E1, ee1, zq1f, k1i);

    gemm_part_k<<<dim3(2, 8), 256, 0, stream>>>(ze1f, h2fw, part, 512, 128, 64);
    combine_k<<<64, 256, 0, stream>>>(part, h2fb, h2a, 128 * 128, 128, 8, 1);
    gemm_part_k<<<dim3(8, 2), 256, 0, stream>>>(h2a, h2f2w, part, 128, 512, 64);
    combine_k<<<256, 256, 0, stream>>>(part, h2f2b, ze2f, 128 * 512, 512, 2, 2);
    vq64_k<<<4, 256, 0, stream>>>(ze2f, E2, ee2, zq2f, k2i);

    gemm_part_k<<<dim3(2, 8), 256, 0, stream>>>(zq2f, h2f3w, part, 512, 128, 64);
    combine_k<<<64, 256, 0, stream>>>(part, h2f3b, h2b, 128 * 128, 128, 8, 1);
    gemm_part_k<<<dim3(8, 2), 256, 0, stream>>>(h2b, h2f4w, part, 128, 512, 64);
    combine_k<<<256, 256, 0, stream>>>(part, h2f4b, decf, 128 * 512, 512, 2, 2);
    blend_k<<<256, 256, 0, stream>>>(zq1f, decf, hier, 1, x1f, 512, 65536);

    gemm_part_k<<<dim3(4, 8), 256, 0, stream>>>(x1f, h1f3w, part, 512, 256, 64);
    combine_k<<<128, 256, 0, stream>>>(part, h1f3b, h1b, 128 * 256, 256, 8, 1);
    gemm_part_k<<<dim3(181, 2), 256, 0, stream>>>(h1b, h1f4w, part, 256, 11552, 128);
    combine_k<<<1024, 256, 0, stream>>>(part, h1f4b, dec0, TOT32, 11552, 2, 2);
    blend_k<<<1024, 256, 0, stream>>>(zq0f, dec0, hier, 0, xf, 11552, TOT32);

    gemm_part_k<<<dim3(6, 16), 256, 0, stream>>>(xf, polw, part, 11552, 362, 722);
    combine_k<<<256, 256, 0, stream>>>(part, polb, polf, 128 * 362, 362, 16, 0);
    value_k<<<128, 256, 0, stream>>>(xf, valw, valb, valf);

    // ---- emit phase: d_out is float32 ----
    emit_f32_k<<<128, 256, 0, stream>>>(polf, out, OUT_POLICY, 46336);
    emit_f32_k<<<1, 128, 0, stream>>>(valf, out, OUT_VALUE, 128);
    emit_f32_k<<<1024, 256, 0, stream>>>(ze0f, out, OUT_ZE0, TOT32);
    emit_f32_k<<<256, 256, 0, stream>>>(ze1f, out, OUT_ZE1, 65536);
    emit_f32_k<<<256, 256, 0, stream>>>(ze2f, out, OUT_ZE2, 65536);
    emit_f32_k<<<1024, 256, 0, stream>>>(zq0f, out, OUT_ZQ0, TOT32);
    emit_f32_k<<<256, 256, 0, stream>>>(zq1f, out, OUT_ZQ1, 65536);
    emit_f32_k<<<256, 256, 0, stream>>>(zq2f, out, OUT_ZQ2, 65536);
    emit_k_k<<<181, 256, 0, stream>>>(k0i, out, OUT_K0, 46208);
    emit_k_k<<<4, 256, 0, stream>>>(k1i, out, OUT_K1, 1024);
    emit_k_k<<<4, 256, 0, stream>>>(k2i, out, OUT_K2, 1024);
    emit_f32_k<<<1024, 256, 0, stream>>>(zq0f, out, OUT_ZQL0, TOT32);
    emit_f32_k<<<256, 256, 0, stream>>>(zq1f, out, OUT_ZQL1, 65536);
    emit_f32_k<<<256, 256, 0, stream>>>(zq2f, out, OUT_ZQL2, 65536);
    emit_em_k<<<1024, 256, 0, stream>>>(cm0, out, OUT_EM0, 32, 361, TOT32);
    emit_em_k<<<256, 256, 0, stream>>>(cm1, out, OUT_EM1, 64, 8, 65536);
    emit_em_k<<<256, 256, 0, stream>>>(cm2, out, OUT_EM2, 64, 8, 65536);
}

// Round 8
// 14405.266 us; speedup vs baseline: 1.6089x; 1.6089x over previous
//
#include <hip/hip_runtime.h>
#include <hip/hip_bf16.h>

typedef long long i64;

// ---- output element offsets (FLOAT32 elements — d_out is float*) ----
static constexpr i64 OUT_POLICY = 0;
static constexpr i64 OUT_VALUE  = 46336;
static constexpr i64 OUT_ZE0    = 46464;
static constexpr i64 OUT_ZE1    = 1525120;
static constexpr i64 OUT_ZE2    = 1590656;
static constexpr i64 OUT_ZQ0    = 1656192;
static constexpr i64 OUT_ZQ1    = 3134848;
static constexpr i64 OUT_ZQ2    = 3200384;
static constexpr i64 OUT_K0     = 3265920;
static constexpr i64 OUT_K1     = 3312128;
static constexpr i64 OUT_K2     = 3313152;
static constexpr i64 OUT_ZQL0   = 3314176;
static constexpr i64 OUT_ZQL1   = 4792832;
static constexpr i64 OUT_ZQL2   = 4858368;
static constexpr i64 OUT_EM0    = 4923904;
static constexpr i64 OUT_EM1    = 6402560;
static constexpr i64 OUT_EM2    = 6468096;
static constexpr i64 OUT_TOTAL  = 6533632;

// =============== weight transpose: w[co][ci][tap] -> wt[tap][ci][co] ===============
__global__ void wtr_k(const float* __restrict__ w, float* __restrict__ wt,
                      int COUT, int CIN)
{
    int total = COUT * CIN * 9;
    for (int idx = blockIdx.x * blockDim.x + threadIdx.x; idx < total;
         idx += gridDim.x * blockDim.x) {
        int co = idx / (CIN * 9);
        int r  = idx - co * CIN * 9;
        int ci = r / 9;
        int tap = r - ci * 9;
        wt[((i64)tap * CIN + ci) * COUT + co] = w[idx];
    }
}

// =============== conv 3x3 SAME as implicit GEMM, f32, no bias ===============
// M-tile 64 co (blockIdx.y), N-tile 128 cols (blockIdx.x; col = n*361+s).
// K = 9 taps x CIN, tap outer / ci inner (step 16). Boundary via per-tap masks.
__global__ __launch_bounds__(256)
void convgemm_k(const float* __restrict__ X,   // [128][CIN][361]
                const float* __restrict__ wt,  // [9][CIN][wtW]
                float* __restrict__ Y,         // [128][coutT][361]
                int CIN, int wtW, int coutT)
{
    __shared__ float Ws[16][64];
    __shared__ float Bs[16][132];
    const int tid  = threadIdx.x;
    const int col0 = blockIdx.x * 128;
    const int co0  = blockIdx.y * 64;
    const int tn = tid & 31, tm = tid >> 5;

    // staging-column info (fixed per thread)
    const int clS  = tid & 127;
    const int kk0  = tid >> 7;            // 0 or 1
    const int colS = col0 + clS;
    const int nS = colS / 361;
    const int sS = colS - nS * 361;
    const int yS = sS / 19, xS = sS - yS * 19;
    const float* Xn = X + (i64)nS * CIN * 361;

    float acc[8][4];
#pragma unroll
    for (int i = 0; i < 8; i++)
#pragma unroll
        for (int j = 0; j < 4; j++) acc[i][j] = 0.f;

    for (int tap = 0; tap < 9; tap++) {
        const int ky = tap / 3, kx = tap - ky * 3;
        const bool vS = (yS + ky >= 1) & (yS + ky <= 19) & (xS + kx >= 1) & (xS + kx <= 19);
        const float* Xs = Xn + sS + (ky - 1) * 19 + (kx - 1);
        const float* wtap = wt + (i64)tap * CIN * wtW;

        for (int cb = 0; cb < CIN; cb += 16) {
            __syncthreads();
            // stage weights: 16x64, coalesced over co
#pragma unroll
            for (int j = 0; j < 4; j++) {
                int e = tid + j * 256;
                int kk = e >> 6, co = e & 63;
                int ci = cb + kk;
                float val = 0.f;
                if (ci < CIN && (co0 + co) < wtW)
                    val = wtap[(i64)ci * wtW + co0 + co];
                Ws[kk][co] = val;
            }
            // stage activations: 16x128, coalesced over cols
#pragma unroll
            for (int j = 0; j < 8; j++) {
                int kk = kk0 + 2 * j;
                int ci = cb + kk;
                float val = 0.f;
                if (vS && ci < CIN) val = Xs[(i64)ci * 361];
                Bs[kk][clS] = val;
            }
            __syncthreads();
#pragma unroll
            for (int kk = 0; kk < 16; kk++) {
                float b0 = Bs[kk][tn * 4 + 0];
                float b1 = Bs[kk][tn * 4 + 1];
                float b2 = Bs[kk][tn * 4 + 2];
                float b3 = Bs[kk][tn * 4 + 3];
#pragma unroll
                for (int i = 0; i < 8; i++) {
                    float wv = Ws[kk][tm * 8 + i];
                    acc[i][0] = fmaf(wv, b0, acc[i][0]);
                    acc[i][1] = fmaf(wv, b1, acc[i][1]);
                    acc[i][2] = fmaf(wv, b2, acc[i][2]);
                    acc[i][3] = fmaf(wv, b3, acc[i][3]);
                }
            }
        }
    }

    // store
#pragma unroll
    for (int j = 0; j < 4; j++) {
        int colT = col0 + tn * 4 + j;
        int nT = colT / 361;
        int sT = colT - nT * 361;
        float* yp = Y + ((i64)nT * coutT + co0) * 361 + sT;
#pragma unroll
        for (int i = 0; i < 8; i++) {
            int co = tm * 8 + i;
            if (co0 + co < coutT) yp[(i64)co * 361] = acc[i][j];
        }
    }
}

// =============== BN batch-stats -> scale/shift ===============
__global__ __launch_bounds__(256)
void bnstats_k(const float* __restrict__ x, const float* __restrict__ g,
               const float* __restrict__ b, float* __restrict__ scale,
               float* __restrict__ shift, int C)
{
    const int c = blockIdx.x;
    float s = 0.f, s2 = 0.f;
    for (int n = 0; n < 128; n++) {
        const float* p = x + ((i64)n * C + c) * 361;
        for (int i = threadIdx.x; i < 361; i += 256) {
            float v = p[i]; s += v; s2 += v * v;
        }
    }
    __shared__ float rs[4], rq[4];
    for (int o = 32; o > 0; o >>= 1) { s += __shfl_down(s, o); s2 += __shfl_down(s2, o); }
    int lane = threadIdx.x & 63, wid = threadIdx.x >> 6;
    if (lane == 0) { rs[wid] = s; rq[wid] = s2; }
    __syncthreads();
    if (threadIdx.x == 0) {
        float S = rs[0] + rs[1] + rs[2] + rs[3];
        float Q = rq[0] + rq[1] + rq[2] + rq[3];
        const float inv = 1.f / 46208.f;
        float m  = S * inv;
        float var = Q * inv - m * m;
        float sc = g[c] * rsqrtf(var + 1e-5f);
        scale[c] = sc;
        shift[c] = b[c] - m * sc;
    }
}

// =============== BN apply variants (ws-only) ===============
__global__ void bn_relu_k(float* __restrict__ x, const float* __restrict__ scale,
                          const float* __restrict__ shift, int C, int total)
{
    for (int i = blockIdx.x * blockDim.x + threadIdx.x; i < total; i += gridDim.x * blockDim.x) {
        int c = (i / 361) % C;
        float v = fmaf(x[i], scale[c], shift[c]);
        x[i] = v > 0.f ? v : 0.f;
    }
}

__global__ void bn_add_relu_slice_k(float* __restrict__ xa, const float* __restrict__ xc,
                                    const float* __restrict__ scale, const float* __restrict__ shift,
                                    int cbase, int total)
{
    for (int i = blockIdx.x * blockDim.x + threadIdx.x; i < total; i += gridDim.x * blockDim.x) {
        int s = i % 361;
        int t = i / 361;
        int ch = t % 64;
        int n = t / 64;
        i64 ai = ((i64)n * 256 + cbase + ch) * 361 + s;
        float v = xa[ai] + fmaf(xc[i], scale[ch], shift[ch]);
        xa[ai] = v > 0.f ? v : 0.f;
    }
}

__global__ void bn_tanh_ws_k(const float* __restrict__ x, const float* __restrict__ scale,
                             const float* __restrict__ shift, float* __restrict__ zf, int total)
{
    for (int i = blockIdx.x * blockDim.x + threadIdx.x; i < total; i += gridDim.x * blockDim.x) {
        int c = (i / 361) & 31;
        zf[i] = tanhf(fmaf(x[i], scale[c], shift[c]));
    }
}

// =============== codebook prep ===============
__global__ void prep_k(const float* __restrict__ E0, const float* __restrict__ E1,
                       const float* __restrict__ E2,
                       float* __restrict__ ee0, float* __restrict__ ee1, float* __restrict__ ee2,
                       float* __restrict__ cm0, float* __restrict__ cm1, float* __restrict__ cm2)
{
    int t = threadIdx.x;
    if (blockIdx.x == 0) {
        float s = 0.f; const float* e = E0 + (i64)t * 32;
        for (int d = 0; d < 32; d++) s += e[d] * e[d];
        ee0[t] = s;
    } else if (blockIdx.x == 1) {
        float s = 0.f; const float* e = E1 + (i64)t * 64;
        for (int d = 0; d < 64; d++) s += e[d] * e[d];
        ee1[t] = s;
    } else if (blockIdx.x == 2) {
        float s = 0.f; const float* e = E2 + (i64)t * 64;
        for (int d = 0; d < 64; d++) s += e[d] * e[d];
        ee2[t] = s;
    } else {
        if (t < 32) {
            float s = 0.f; for (int k = 0; k < 512; k++) s += E0[k * 32 + t];
            cm0[t] = s * (1.f / 512.f);
        } else if (t >= 64 && t < 128) {
            int d = t - 64; float s = 0.f; for (int k = 0; k < 512; k++) s += E1[k * 64 + d];
            cm1[d] = s * (1.f / 512.f);
        } else if (t >= 128 && t < 192) {
            int d = t - 128; float s = 0.f; for (int k = 0; k < 512; k++) s += E2[k * 64 + d];
            cm2[d] = s * (1.f / 512.f);
        }
    }
}

// =============== VQ kernels (32 KB LDS, multi-pass staging) ===============
__global__ __launch_bounds__(256)
void vq0_k(const float* __restrict__ z, const float* __restrict__ E,
           const float* __restrict__ ee, float* __restrict__ zqf, int* __restrict__ ki)
{
    __shared__ float Es[256 * 32];
    int row = blockIdx.x * 256 + threadIdx.x;
    const bool live = row < 46208;
    const float* zp = z + (i64)(live ? row : 0) * 32;
    float zv[32]; float zz = 0.f;
#pragma unroll
    for (int d = 0; d < 32; d++) { float v = zp[d]; zv[d] = v; zz += v * v; }
    float best = 3.4e38f; int bk = 0;
    for (int h = 0; h < 2; h++) {
        __syncthreads();
        for (int i = threadIdx.x; i < 256 * 32; i += 256) Es[i] = E[h * 8192 + i];
        __syncthreads();
        for (int k = 0; k < 256; k++) {
            const float* e = Es + k * 32;
            float dot = 0.f;
#pragma unroll
            for (int d = 0; d < 32; d++) dot = fmaf(zv[d], e[d], dot);
            float dist = (zz + ee[h * 256 + k]) - 2.f * dot;
            if (dist < best) { best = dist; bk = h * 256 + k; }
        }
    }
    if (live) {
        ki[row] = bk;
        const float* eb = E + (i64)bk * 32;
#pragma unroll
        for (int d = 0; d < 32; d++) zqf[(i64)row * 32 + d] = eb[d];
    }
}

__global__ __launch_bounds__(256)
void vq64_k(const float* __restrict__ z, const float* __restrict__ E,
            const float* __restrict__ ee, float* __restrict__ zqf, int* __restrict__ ki)
{
    __shared__ float Es[128 * 64];
    int row = blockIdx.x * 256 + threadIdx.x;
    const float* zp = z + (i64)row * 64;
    float zv[64]; float zz = 0.f;
#pragma unroll
    for (int d = 0; d < 64; d++) { float v = zp[d]; zv[d] = v; zz += v * v; }
    float best = 3.4e38f; int bk = 0;
    for (int h = 0; h < 4; h++) {
        __syncthreads();
        for (int i = threadIdx.x; i < 128 * 64; i += 256) Es[i] = E[(i64)h * 8192 + i];
        __syncthreads();
        for (int k = 0; k < 128; k++) {
            const float* e = Es + k * 64;
            float dot = 0.f;
#pragma unroll
            for (int d = 0; d < 64; d++) dot = fmaf(zv[d], e[d], dot);
            float dist = (zz + ee[h * 128 + k]) - 2.f * dot;
            if (dist < best) { best = dist; bk = h * 128 + k; }
        }
    }
    ki[row] = bk;
    const float* eb = E + (i64)bk * 64;
#pragma unroll
    for (int d = 0; d < 64; d++) zqf[(i64)row * 64 + d] = eb[d];
}

// =============== split-K GEMM ===============
__global__ __launch_bounds__(256)
void gemm_part_k(const float* __restrict__ A, const float* __restrict__ W,
                 float* __restrict__ part, int K, int N, int kchunk)
{
    __shared__ float As[128][17];
    __shared__ float Ws[16][64];
    const int n0 = blockIdx.x * 64;
    const int ks = blockIdx.y;
    const int kb0  = ks * kchunk;
    const int kend = min(K, kb0 + kchunk);
    const int tid = threadIdx.x;
    const int tn = tid & 15, tm = tid >> 4;
    float acc[8][4];
#pragma unroll
    for (int i = 0; i < 8; i++)
#pragma unroll
        for (int j = 0; j < 4; j++) acc[i][j] = 0.f;

    for (int kb = kb0; kb < kend; kb += 16) {
        __syncthreads();
        for (int i = tid; i < 2048; i += 256) {
            int m = i >> 4, kk = i & 15;
            int k = kb + kk;
            As[m][kk] = (k < kend) ? A[(i64)m * K + k] : 0.f;
        }
        for (int i = tid; i < 1024; i += 256) {
            int kk = i >> 6, nl = i & 63;
            int k = kb + kk, n = n0 + nl;
            Ws[kk][nl] = (k < kend && n < N) ? W[(i64)k * N + n] : 0.f;
        }
        __syncthreads();
#pragma unroll
        for (int kk = 0; kk < 16; kk++) {
            float av[8], wv[4];
#pragma unroll
            for (int i = 0; i < 8; i++) av[i] = As[tm * 8 + i][kk];
#pragma unroll
            for (int j = 0; j < 4; j++) wv[j] = Ws[kk][tn * 4 + j];
#pragma unroll
            for (int i = 0; i < 8; i++)
#pragma unroll
                for (int j = 0; j < 4; j++) acc[i][j] = fmaf(av[i], wv[j], acc[i][j]);
        }
    }
#pragma unroll
    for (int i = 0; i < 8; i++) {
        int m = tm * 8 + i;
#pragma unroll
        for (int j = 0; j < 4; j++) {
            int n = n0 + tn * 4 + j;
            if (n < N) part[((i64)ks * 128 + m) * N + n] = acc[i][j];
        }
    }
}

__global__ void combine_k(const float* __restrict__ part, const float* __restrict__ bias,
                          float* __restrict__ of, int MN, int N, int ksplit, int act)
{
    for (int i = blockIdx.x * blockDim.x + threadIdx.x; i < MN; i += gridDim.x * blockDim.x) {
        float s = 0.f;
        for (int t = 0; t < ksplit; t++) s += part[(i64)t * MN + i];
        s += bias[i % N];
        if (act == 1) s = s > 0.f ? s : 0.f;
        else if (act == 2) s = tanhf(s);
        of[i] = s;
    }
}

__global__ void blend_k(const float* __restrict__ q, const float* __restrict__ d,
                        const float* __restrict__ hu, int col, float* __restrict__ o,
                        int per_b, int total)
{
    for (int i = blockIdx.x * blockDim.x + threadIdx.x; i < total; i += gridDim.x * blockDim.x) {
        float u = hu[(i / per_b) * 2 + col];
        o[i] = u * q[i] + (1.f - u) * d[i];
    }
}

__global__ __launch_bounds__(256)
void value_k(const float* __restrict__ x, const float* __restrict__ w,
             const float* __restrict__ b, float* __restrict__ valf)
{
    int m = blockIdx.x;
    float s = 0.f;
    const float* xp = x + (i64)m * 11552;
    for (int k = threadIdx.x; k < 11552; k += 256) s = fmaf(xp[k], w[k], s);
    for (int o = 32; o > 0; o >>= 1) s += __shfl_down(s, o);
    __shared__ float r[4];
    int lane = threadIdx.x & 63, wid = threadIdx.x >> 6;
    if (lane == 0) r[wid] = s;
    __syncthreads();
    if (threadIdx.x == 0)
        valf[m] = tanhf(r[0] + r[1] + r[2] + r[3] + b[0]);
}

// =============== emit phase (d_out is FLOAT32) ===============
__global__ void emit_f32_k(const float* __restrict__ src, float* __restrict__ out, i64 off, int n)
{
    for (int i = blockIdx.x * blockDim.x + threadIdx.x; i < n; i += gridDim.x * blockDim.x)
        out[off + i] = src[i];
}

__global__ void emit_k_k(const int* __restrict__ ki, float* __restrict__ out, i64 off, int n)
{
    for (int i = blockIdx.x * blockDim.x + threadIdx.x; i < n; i += gridDim.x * blockDim.x)
        out[off + i] = (float)ki[i];
}

__global__ void emit_em_k(const float* __restrict__ cm, float* __restrict__ out, i64 off,
                          int D, int SPL, int total)
{
    for (int i = blockIdx.x * blockDim.x + threadIdx.x; i < total; i += gridDim.x * blockDim.x) {
        int c = (i / SPL) % D;
        out[off + i] = cm[c];
    }
}

// =============== guard markers ===============
__global__ void marker_k(float* __restrict__ out, int code)
{
    if (threadIdx.x < 64) out[threadIdx.x] = 3000.f + 100.f * code;
}

__global__ void sentinel_k(float* __restrict__ out)
{
    if (threadIdx.x < 128) out[OUT_VALUE + threadIdx.x] = 2000.0f;
}

// ===================== host launch =====================
extern "C" void kernel_launch(void* const* d_in, const int* in_sizes, int n_in,
                              void* d_out, int out_size, void* d_ws, size_t ws_size,
                              hipStream_t stream)
{
    float* out = (float*)d_out;

    int bad = -1;
    if (out_size != (int)OUT_TOTAL) bad = 0;
    else if (n_in != 41) bad = 1;
    else if (in_sizes[0] != 128 * 18 * 361) bad = 2;
    else if (in_sizes[21] != 11552 * 256) bad = 3;
    if (bad >= 0) { marker_k<<<1, 64, 0, stream>>>(out, bad); return; }

    const float* obs   = (const float*)d_in[0];
    const float* hier  = (const float*)d_in[1];
    const float* c0w   = (const float*)d_in[2];
    const float* bn0g  = (const float*)d_in[4];
    const float* bn0b  = (const float*)d_in[5];
    const float* rb1w  = (const float*)d_in[6];
    const float* rbn1g = (const float*)d_in[8];
    const float* rbn1b = (const float*)d_in[9];
    const float* rb2w  = (const float*)d_in[10];
    const float* rbn2g = (const float*)d_in[12];
    const float* rbn2b = (const float*)d_in[13];
    const float* c2w   = (const float*)d_in[14];
    const float* bn2g  = (const float*)d_in[16];
    const float* bn2b  = (const float*)d_in[17];
    const float* E0    = (const float*)d_in[18];
    const float* E1    = (const float*)d_in[19];
    const float* E2    = (const float*)d_in[20];
    const float* fc1w  = (const float*)d_in[21]; const float* fc1b  = (const float*)d_in[22];
    const float* fc2w  = (const float*)d_in[23]; const float* fc2b  = (const float*)d_in[24];
    const float* h2fw  = (const float*)d_in[25]; const float* h2fb  = (const float*)d_in[26];
    const float* h2f2w = (const float*)d_in[27]; const float* h2f2b = (const float*)d_in[28];
    const float* h2f3w = (const float*)d_in[29]; const float* h2f3b = (const float*)d_in[30];
    const float* h2f4w = (const float*)d_in[31]; const float* h2f4b = (const float*)d_in[32];
    const float* h1f3w = (const float*)d_in[33]; const float* h1f3b = (const float*)d_in[34];
    const float* h1f4w = (const float*)d_in[35]; const float* h1f4b = (const float*)d_in[36];
    const float* polw  = (const float*)d_in[37]; const float* polb  = (const float*)d_in[38];
    const float* valw  = (const float*)d_in[39]; const float* valb  = (const float*)d_in[40];

    float* wsf = (float*)d_ws;

    // ws need: 27,271,168 (old) + 589,824 (WT) = 27,860,992 floats = 111.44 MB
    const size_t NEED_BYTES = (size_t)27860992 * 4;
    if (ws_size < NEED_BYTES) {
        sentinel_k<<<1, 128, 0, stream>>>(out);
        return;
    }

    float* scale = wsf + 0;        float* shift = wsf + 256;
    float* ee0 = wsf + 512;        float* ee1 = wsf + 1024;   float* ee2 = wsf + 1536;
    float* cm0 = wsf + 2048;       float* cm1 = wsf + 2112;   float* cm2 = wsf + 2176;
    int*   k0i = (int*)(wsf + 4096);
    int*   k1i = (int*)(wsf + 50304);
    int*   k2i = (int*)(wsf + 51328);
    float* h1a  = wsf + 53248;
    float* ze1f = wsf + 86016;
    float* zq1f = wsf + 151552;
    float* h2a  = wsf + 217088;
    float* ze2f = wsf + 233472;
    float* zq2f = wsf + 299008;
    float* h2b  = wsf + 364544;
    float* decf = wsf + 380928;
    float* x1f  = wsf + 446464;
    float* h1b  = wsf + 512000;
    float* polf = wsf + 544768;
    float* valf = wsf + 591104;

    float* A    = wsf + 655360;
    float* B    = wsf + 12484608;
    float* C64  = wsf + 24313856;
    float* WT   = wsf + 27271168;        // 589,824 floats (weight transpose)
    float* ze0f = A;
    float* zq0f = wsf + 655360 + 1572864;
    float* dec0 = wsf + 655360 + 3145728;
    float* xf   = wsf + 655360 + 4718592;
    float* part = B;

    const int TOT256 = 128 * 256 * 361;
    const int TOT32  = 128 * 32 * 361;
    const int TOT64  = 128 * 64 * 361;

    prep_k<<<4, 512, 0, stream>>>(E0, E1, E2, ee0, ee1, ee2, cm0, cm1, cm2);

    // ---- trunk (implicit-GEMM convs) ----
    wtr_k<<<64, 256, 0, stream>>>(c0w, WT, 256, 18);
    convgemm_k<<<dim3(361, 4), 256, 0, stream>>>(obs, WT, A, 18, 256, 256);
    bnstats_k<<<256, 256, 0, stream>>>(A, bn0g, bn0b, scale, shift, 256);
    bn_relu_k<<<1024, 256, 0, stream>>>(A, scale, shift, 256, TOT256);

    for (int i = 0; i < 3; i++) {
        wtr_k<<<576, 256, 0, stream>>>(rb1w + (i64)i * 589824, WT, 256, 256);
        convgemm_k<<<dim3(361, 4), 256, 0, stream>>>(A, WT, B, 256, 256, 256);
        bnstats_k<<<256, 256, 0, stream>>>(B, rbn1g + i * 256, rbn1b + i * 256, scale, shift, 256);
        bn_relu_k<<<1024, 256, 0, stream>>>(B, scale, shift, 256, TOT256);
        for (int c = 0; c < 4; c++) {
            wtr_k<<<144, 256, 0, stream>>>(rb2w + (i64)i * 589824 + (i64)c * 64 * 256 * 9, WT, 64, 256);
            convgemm_k<<<dim3(361, 1), 256, 0, stream>>>(B, WT, C64, 256, 64, 64);
            bnstats_k<<<64, 256, 0, stream>>>(C64, rbn2g + i * 256 + c * 64,
                                              rbn2b + i * 256 + c * 64, scale, shift, 64);
            bn_add_relu_slice_k<<<1024, 256, 0, stream>>>(A, C64, scale, shift, c * 64, TOT64);
        }
    }

    wtr_k<<<72, 256, 0, stream>>>(c2w, WT, 32, 256);
    convgemm_k<<<dim3(361, 1), 256, 0, stream>>>(A, WT, C64, 256, 32, 32);
    bnstats_k<<<32, 256, 0, stream>>>(C64, bn2g, bn2b, scale, shift, 32);
    bn_tanh_ws_k<<<1024, 256, 0, stream>>>(C64, scale, shift, ze0f, TOT32);

    vq0_k<<<181, 256, 0, stream>>>(ze0f, E0, ee0, zq0f, k0i);

    gemm_part_k<<<dim3(4, 32), 256, 0, stream>>>(ze0f, fc1w, part, 11552, 256, 361);
    combine_k<<<128, 256, 0, stream>>>(part, fc1b, h1a, 128 * 256, 256, 32, 1);
    gemm_part_k<<<dim3(8, 4), 256, 0, stream>>>(h1a, fc2w, part, 256, 512, 64);
    combine_k<<<256, 256, 0, stream>>>(part, fc2b, ze1f, 128 * 512, 512, 4, 2);
    vq64_k<<<4, 256, 0, stream>>>(ze1f, E1, ee1, zq1f, k1i);

    gemm_part_k<<<dim3(2, 8), 256, 0, stream>>>(ze1f, h2fw, part, 512, 128, 64);
    combine_k<<<64, 256, 0, stream>>>(part, h2fb, h2a, 128 * 128, 128, 8, 1);
    gemm_part_k<<<dim3(8, 2), 256, 0, stream>>>(h2a, h2f2w, part, 128, 512, 64);
    combine_k<<<256, 256, 0, stream>>>(part, h2f2b, ze2f, 128 * 512, 512, 2, 2);
    vq64_k<<<4, 256, 0, stream>>>(ze2f, E2, ee2, zq2f, k2i);

    gemm_part_k<<<dim3(2, 8), 256, 0, stream>>>(zq2f, h2f3w, part, 512, 128, 64);
    combine_k<<<64, 256, 0, stream>>>(part, h2f3b, h2b, 128 * 128, 128, 8, 1);
    gemm_part_k<<<dim3(8, 2), 256, 0, stream>>>(h2b, h2f4w, part, 128, 512, 64);
    combine_k<<<256, 256, 0, stream>>>(part, h2f4b, decf, 128 * 512, 512, 2, 2);
    blend_k<<<256, 256, 0, stream>>>(zq1f, decf, hier, 1, x1f, 512, 65536);

    gemm_part_k<<<dim3(4, 8), 256, 0, stream>>>(x1f, h1f3w, part, 512, 256, 64);
    combine_k<<<128, 256, 0, stream>>>(part, h1f3b, h1b, 128 * 256, 256, 8, 1);
    gemm_part_k<<<dim3(181, 2), 256, 0, stream>>>(h1b, h1f4w, part, 256, 11552, 128);
    combine_k<<<1024, 256, 0, stream>>>(part, h1f4b, dec0, TOT32, 11552, 2, 2);
    blend_k<<<1024, 256, 0, stream>>>(zq0f, dec0, hier, 0, xf, 11552, TOT32);

    gemm_part_k<<<dim3(6, 16), 256, 0, stream>>>(xf, polw, part, 11552, 362, 722);
    combine_k<<<256, 256, 0, stream>>>(part, polb, polf, 128 * 362, 362, 16, 0);
    value_k<<<128, 256, 0, stream>>>(xf, valw, valb, valf);

    // ---- emit phase: d_out is float32 ----
    emit_f32_k<<<128, 256, 0, stream>>>(polf, out, OUT_POLICY, 46336);
    emit_f32_k<<<1, 128, 0, stream>>>(valf, out, OUT_VALUE, 128);
    emit_f32_k<<<1024, 256, 0, stream>>>(ze0f, out, OUT_ZE0, TOT32);
    emit_f32_k<<<256, 256, 0, stream>>>(ze1f, out, OUT_ZE1, 65536);
    emit_f32_k<<<256, 256, 0, stream>>>(ze2f, out, OUT_ZE2, 65536);
    emit_f32_k<<<1024, 256, 0, stream>>>(zq0f, out, OUT_ZQ0, TOT32);
    emit_f32_k<<<256, 256, 0, stream>>>(zq1f, out, OUT_ZQ1, 65536);
    emit_f32_k<<<256, 256, 0, stream>>>(zq2f, out, OUT_ZQ2, 65536);
    emit_k_k<<<181, 256, 0, stream>>>(k0i, out, OUT_K0, 46208);
    emit_k_k<<<4, 256, 0, stream>>>(k1i, out, OUT_K1, 1024);
    emit_k_k<<<4, 256, 0, stream>>>(k2i, out, OUT_K2, 1024);
    emit_f32_k<<<1024, 256, 0, stream>>>(zq0f, out, OUT_ZQL0, TOT32);
    emit_f32_k<<<256, 256, 0, stream>>>(zq1f, out, OUT_ZQL1, 65536);
    emit_f32_k<<<256, 256, 0, stream>>>(zq2f, out, OUT_ZQL2, 65536);
    emit_em_k<<<1024, 256, 0, stream>>>(cm0, out, OUT_EM0, 32, 361, TOT32);
    emit_em_k<<<256, 256, 0, stream>>>(cm1, out, OUT_EM1, 64, 8, 65536);
    emit_em_k<<<256, 256, 0, stream>>>(cm2, out, OUT_EM2, 64, 8, 65536);
}

// Round 9
// 9415.633 us; speedup vs baseline: 2.4615x; 1.5299x over previous
//
#include <hip/hip_runtime.h>
#include <hip/hip_bf16.h>

typedef long long i64;

// ---- output element offsets (FLOAT32 elements — d_out is float*) ----
static constexpr i64 OUT_POLICY = 0;
static constexpr i64 OUT_VALUE  = 46336;
static constexpr i64 OUT_ZE0    = 46464;
static constexpr i64 OUT_ZE1    = 1525120;
static constexpr i64 OUT_ZE2    = 1590656;
static constexpr i64 OUT_ZQ0    = 1656192;
static constexpr i64 OUT_ZQ1    = 3134848;
static constexpr i64 OUT_ZQ2    = 3200384;
static constexpr i64 OUT_K0     = 3265920;
static constexpr i64 OUT_K1     = 3312128;
static constexpr i64 OUT_K2     = 3313152;
static constexpr i64 OUT_ZQL0   = 3314176;
static constexpr i64 OUT_ZQL1   = 4792832;
static constexpr i64 OUT_ZQL2   = 4858368;
static constexpr i64 OUT_EM0    = 4923904;
static constexpr i64 OUT_EM1    = 6402560;
static constexpr i64 OUT_EM2    = 6468096;
static constexpr i64 OUT_TOTAL  = 6533632;

// =============== weight transpose: w[co][ci][tap] -> wt[tap][ci][co] ===============
__global__ void wtr_k(const float* __restrict__ w, float* __restrict__ wt,
                      int COUT, int CIN)
{
    int total = COUT * CIN * 9;
    for (int idx = blockIdx.x * blockDim.x + threadIdx.x; idx < total;
         idx += gridDim.x * blockDim.x) {
        int co = idx / (CIN * 9);
        int r  = idx - co * CIN * 9;
        int ci = r / 9;
        int tap = r - ci * 9;
        wt[((i64)tap * CIN + ci) * COUT + co] = w[idx];
    }
}

// =============== conv 3x3 SAME as implicit GEMM, f32, software-pipelined ===============
// M-tile 64 co, N-tile 128 cols. K = 9 taps x CIN, step 16. Double-buffered LDS;
// next step's globals prefetched into registers during current compute (T14).
template<int CIN>
__global__ __launch_bounds__(256)
void convgemm_k(const float* __restrict__ X,   // [128][CIN][361]
                const float* __restrict__ wt,  // [9][CIN][wtW]
                float* __restrict__ Y,         // [128][coutT][361]
                int wtW, int coW0, int coutT)
{
    constexpr int NCB = (CIN + 15) / 16;
    constexpr int NS  = 9 * NCB;
    __shared__ float Ws[2][16][64];
    __shared__ float Bs[2][16][132];
    const int tid  = threadIdx.x;
    const int col0 = blockIdx.x * 128;
    const int co0  = blockIdx.y * 64;
    const int tn = tid & 31, tm = tid >> 5;

    // staging-column info (fixed per thread)
    const int clS  = tid & 127;
    const int kk0  = tid >> 7;            // 0 or 1
    const int colS = col0 + clS;
    const int nS = colS / 361;
    const int sS = colS - nS * 361;
    const int yS = sS / 19, xS = sS - yS * 19;
    const float* Xn = X + (i64)nS * CIN * 361 + sS;

    float wr0, wr1, wr2, wr3;
    float br0, br1, br2, br3, br4, br5, br6, br7;

#define STAGE(S)                                                                \
    {                                                                           \
        const int tap_ = (S) / NCB, cb_ = ((S) - tap_ * NCB) * 16;              \
        const int ky_ = tap_ / 3, kx_ = tap_ - ky_ * 3;                         \
        const bool vS_ = (yS + ky_ >= 1) & (yS + ky_ <= 19) &                   \
                         (xS + kx_ >= 1) & (xS + kx_ <= 19);                    \
        const float* Xs_ = Xn + (ky_ - 1) * 19 + (kx_ - 1);                     \
        const float* wt_ = wt + ((i64)tap_ * CIN + cb_) * wtW + coW0 + co0;     \
        const int kw_ = tid >> 6, cw_ = tid & 63;                               \
        const bool wok_ = (coW0 + co0 + cw_) < wtW;                             \
        wr0 = (wok_ && cb_ + kw_      < CIN) ? wt_[(i64)(kw_     ) * wtW + cw_] : 0.f; \
        wr1 = (wok_ && cb_ + kw_ + 4  < CIN) ? wt_[(i64)(kw_ + 4 ) * wtW + cw_] : 0.f; \
        wr2 = (wok_ && cb_ + kw_ + 8  < CIN) ? wt_[(i64)(kw_ + 8 ) * wtW + cw_] : 0.f; \
        wr3 = (wok_ && cb_ + kw_ + 12 < CIN) ? wt_[(i64)(kw_ + 12) * wtW + cw_] : 0.f; \
        br0 = (vS_ && cb_ + kk0      < CIN) ? Xs_[(i64)(cb_ + kk0     ) * 361] : 0.f; \
        br1 = (vS_ && cb_ + kk0 + 2  < CIN) ? Xs_[(i64)(cb_ + kk0 + 2 ) * 361] : 0.f; \
        br2 = (vS_ && cb_ + kk0 + 4  < CIN) ? Xs_[(i64)(cb_ + kk0 + 4 ) * 361] : 0.f; \
        br3 = (vS_ && cb_ + kk0 + 6  < CIN) ? Xs_[(i64)(cb_ + kk0 + 6 ) * 361] : 0.f; \
        br4 = (vS_ && cb_ + kk0 + 8  < CIN) ? Xs_[(i64)(cb_ + kk0 + 8 ) * 361] : 0.f; \
        br5 = (vS_ && cb_ + kk0 + 10 < CIN) ? Xs_[(i64)(cb_ + kk0 + 10) * 361] : 0.f; \
        br6 = (vS_ && cb_ + kk0 + 12 < CIN) ? Xs_[(i64)(cb_ + kk0 + 12) * 361] : 0.f; \
        br7 = (vS_ && cb_ + kk0 + 14 < CIN) ? Xs_[(i64)(cb_ + kk0 + 14) * 361] : 0.f; \
    }

#define WRITE(BUF)                                                              \
    {                                                                           \
        const int kw_ = tid >> 6, cw_ = tid & 63;                               \
        Ws[BUF][kw_     ][cw_] = wr0;  Ws[BUF][kw_ + 4 ][cw_] = wr1;            \
        Ws[BUF][kw_ + 8 ][cw_] = wr2;  Ws[BUF][kw_ + 12][cw_] = wr3;            \
        Bs[BUF][kk0     ][clS] = br0;  Bs[BUF][kk0 + 2 ][clS] = br1;            \
        Bs[BUF][kk0 + 4 ][clS] = br2;  Bs[BUF][kk0 + 6 ][clS] = br3;            \
        Bs[BUF][kk0 + 8 ][clS] = br4;  Bs[BUF][kk0 + 10][clS] = br5;            \
        Bs[BUF][kk0 + 12][clS] = br6;  Bs[BUF][kk0 + 14][clS] = br7;            \
    }

    float acc[8][4];
#pragma unroll
    for (int i = 0; i < 8; i++)
#pragma unroll
        for (int j = 0; j < 4; j++) acc[i][j] = 0.f;

    STAGE(0)
    WRITE(0)
    int cur = 0;
    for (int s = 0; s < NS; s++) {
        if (s + 1 < NS) STAGE(s + 1)          // globals in flight during compute
        __syncthreads();                       // buf[cur] ready; prev compute done
#pragma unroll
        for (int kk = 0; kk < 16; kk++) {
            const float4 bv = *reinterpret_cast<const float4*>(&Bs[cur][kk][tn * 4]);
            const float4 w0 = *reinterpret_cast<const float4*>(&Ws[cur][kk][tm * 8]);
            const float4 w1 = *reinterpret_cast<const float4*>(&Ws[cur][kk][tm * 8 + 4]);
            acc[0][0] = fmaf(w0.x, bv.x, acc[0][0]); acc[0][1] = fmaf(w0.x, bv.y, acc[0][1]);
            acc[0][2] = fmaf(w0.x, bv.z, acc[0][2]); acc[0][3] = fmaf(w0.x, bv.w, acc[0][3]);
            acc[1][0] = fmaf(w0.y, bv.x, acc[1][0]); acc[1][1] = fmaf(w0.y, bv.y, acc[1][1]);
            acc[1][2] = fmaf(w0.y, bv.z, acc[1][2]); acc[1][3] = fmaf(w0.y, bv.w, acc[1][3]);
            acc[2][0] = fmaf(w0.z, bv.x, acc[2][0]); acc[2][1] = fmaf(w0.z, bv.y, acc[2][1]);
            acc[2][2] = fmaf(w0.z, bv.z, acc[2][2]); acc[2][3] = fmaf(w0.z, bv.w, acc[2][3]);
            acc[3][0] = fmaf(w0.w, bv.x, acc[3][0]); acc[3][1] = fmaf(w0.w, bv.y, acc[3][1]);
            acc[3][2] = fmaf(w0.w, bv.z, acc[3][2]); acc[3][3] = fmaf(w0.w, bv.w, acc[3][3]);
            acc[4][0] = fmaf(w1.x, bv.x, acc[4][0]); acc[4][1] = fmaf(w1.x, bv.y, acc[4][1]);
            acc[4][2] = fmaf(w1.x, bv.z, acc[4][2]); acc[4][3] = fmaf(w1.x, bv.w, acc[4][3]);
            acc[5][0] = fmaf(w1.y, bv.x, acc[5][0]); acc[5][1] = fmaf(w1.y, bv.y, acc[5][1]);
            acc[5][2] = fmaf(w1.y, bv.z, acc[5][2]); acc[5][3] = fmaf(w1.y, bv.w, acc[5][3]);
            acc[6][0] = fmaf(w1.z, bv.x, acc[6][0]); acc[6][1] = fmaf(w1.z, bv.y, acc[6][1]);
            acc[6][2] = fmaf(w1.z, bv.z, acc[6][2]); acc[6][3] = fmaf(w1.z, bv.w, acc[6][3]);
            acc[7][0] = fmaf(w1.w, bv.x, acc[7][0]); acc[7][1] = fmaf(w1.w, bv.y, acc[7][1]);
            acc[7][2] = fmaf(w1.w, bv.z, acc[7][2]); acc[7][3] = fmaf(w1.w, bv.w, acc[7][3]);
        }
        if (s + 1 < NS) WRITE(cur ^ 1)        // vmcnt wait lands here, not before compute
        cur ^= 1;
    }
#undef STAGE
#undef WRITE

    // store
#pragma unroll
    for (int j = 0; j < 4; j++) {
        int colT = col0 + tn * 4 + j;
        int nT = colT / 361;
        int sT = colT - nT * 361;
        float* yp = Y + ((i64)nT * coutT + co0) * 361 + sT;
#pragma unroll
        for (int i = 0; i < 8; i++) {
            int co = tm * 8 + i;
            if (co0 + co < coutT) yp[(i64)co * 361] = acc[i][j];
        }
    }
}

// =============== BN batch-stats -> scale/shift ===============
__global__ __launch_bounds__(256)
void bnstats_k(const float* __restrict__ x, const float* __restrict__ g,
               const float* __restrict__ b, float* __restrict__ scale,
               float* __restrict__ shift, int C)
{
    const int c = blockIdx.x;
    float s = 0.f, s2 = 0.f;
    for (int n = 0; n < 128; n++) {
        const float* p = x + ((i64)n * C + c) * 361;
        for (int i = threadIdx.x; i < 361; i += 256) {
            float v = p[i]; s += v; s2 += v * v;
        }
    }
    __shared__ float rs[4], rq[4];
    for (int o = 32; o > 0; o >>= 1) { s += __shfl_down(s, o); s2 += __shfl_down(s2, o); }
    int lane = threadIdx.x & 63, wid = threadIdx.x >> 6;
    if (lane == 0) { rs[wid] = s; rq[wid] = s2; }
    __syncthreads();
    if (threadIdx.x == 0) {
        float S = rs[0] + rs[1] + rs[2] + rs[3];
        float Q = rq[0] + rq[1] + rq[2] + rq[3];
        const float inv = 1.f / 46208.f;
        float m  = S * inv;
        float var = Q * inv - m * m;
        float sc = g[c] * rsqrtf(var + 1e-5f);
        scale[c] = sc;
        shift[c] = b[c] - m * sc;
    }
}

// =============== BN apply variants (ws-only) ===============
__global__ void bn_relu_k(float* __restrict__ x, const float* __restrict__ scale,
                          const float* __restrict__ shift, int C, int total)
{
    for (int i = blockIdx.x * blockDim.x + threadIdx.x; i < total; i += gridDim.x * blockDim.x) {
        int c = (i / 361) % C;
        float v = fmaf(x[i], scale[c], shift[c]);
        x[i] = v > 0.f ? v : 0.f;
    }
}

__global__ void bn_add_relu_slice_k(float* __restrict__ xa, const float* __restrict__ xc,
                                    const float* __restrict__ scale, const float* __restrict__ shift,
                                    int cbase, int total)
{
    for (int i = blockIdx.x * blockDim.x + threadIdx.x; i < total; i += gridDim.x * blockDim.x) {
        int s = i % 361;
        int t = i / 361;
        int ch = t % 64;
        int n = t / 64;
        i64 ai = ((i64)n * 256 + cbase + ch) * 361 + s;
        float v = xa[ai] + fmaf(xc[i], scale[ch], shift[ch]);
        xa[ai] = v > 0.f ? v : 0.f;
    }
}

__global__ void bn_tanh_ws_k(const float* __restrict__ x, const float* __restrict__ scale,
                             const float* __restrict__ shift, float* __restrict__ zf, int total)
{
    for (int i = blockIdx.x * blockDim.x + threadIdx.x; i < total; i += gridDim.x * blockDim.x) {
        int c = (i / 361) & 31;
        zf[i] = tanhf(fmaf(x[i], scale[c], shift[c]));
    }
}

// =============== codebook prep ===============
__global__ void prep_k(const float* __restrict__ E0, const float* __restrict__ E1,
                       const float* __restrict__ E2,
                       float* __restrict__ ee0, float* __restrict__ ee1, float* __restrict__ ee2,
                       float* __restrict__ cm0, float* __restrict__ cm1, float* __restrict__ cm2)
{
    int t = threadIdx.x;
    if (blockIdx.x == 0) {
        float s = 0.f; const float* e = E0 + (i64)t * 32;
        for (int d = 0; d < 32; d++) s += e[d] * e[d];
        ee0[t] = s;
    } else if (blockIdx.x == 1) {
        float s = 0.f; const float* e = E1 + (i64)t * 64;
        for (int d = 0; d < 64; d++) s += e[d] * e[d];
        ee1[t] = s;
    } else if (blockIdx.x == 2) {
        float s = 0.f; const float* e = E2 + (i64)t * 64;
        for (int d = 0; d < 64; d++) s += e[d] * e[d];
        ee2[t] = s;
    } else {
        if (t < 32) {
            float s = 0.f; for (int k = 0; k < 512; k++) s += E0[k * 32 + t];
            cm0[t] = s * (1.f / 512.f);
        } else if (t >= 64 && t < 128) {
            int d = t - 64; float s = 0.f; for (int k = 0; k < 512; k++) s += E1[k * 64 + d];
            cm1[d] = s * (1.f / 512.f);
        } else if (t >= 128 && t < 192) {
            int d = t - 128; float s = 0.f; for (int k = 0; k < 512; k++) s += E2[k * 64 + d];
            cm2[d] = s * (1.f / 512.f);
        }
    }
}

// =============== VQ kernels (32 KB LDS, multi-pass staging) ===============
__global__ __launch_bounds__(256)
void vq0_k(const float* __restrict__ z, const float* __restrict__ E,
           const float* __restrict__ ee, float* __restrict__ zqf, int* __restrict__ ki)
{
    __shared__ float Es[256 * 32];
    int row = blockIdx.x * 256 + threadIdx.x;
    const bool live = row < 46208;
    const float* zp = z + (i64)(live ? row : 0) * 32;
    float zv[32]; float zz = 0.f;
#pragma unroll
    for (int d = 0; d < 32; d++) { float v = zp[d]; zv[d] = v; zz += v * v; }
    float best = 3.4e38f; int bk = 0;
    for (int h = 0; h < 2; h++) {
        __syncthreads();
        for (int i = threadIdx.x; i < 256 * 32; i += 256) Es[i] = E[h * 8192 + i];
        __syncthreads();
        for (int k = 0; k < 256; k++) {
            const float* e = Es + k * 32;
            float dot = 0.f;
#pragma unroll
            for (int d = 0; d < 32; d++) dot = fmaf(zv[d], e[d], dot);
            float dist = (zz + ee[h * 256 + k]) - 2.f * dot;
            if (dist < best) { best = dist; bk = h * 256 + k; }
        }
    }
    if (live) {
        ki[row] = bk;
        const float* eb = E + (i64)bk * 32;
#pragma unroll
        for (int d = 0; d < 32; d++) zqf[(i64)row * 32 + d] = eb[d];
    }
}

__global__ __launch_bounds__(256)
void vq64_k(const float* __restrict__ z, const float* __restrict__ E,
            const float* __restrict__ ee, float* __restrict__ zqf, int* __restrict__ ki)
{
    __shared__ float Es[128 * 64];
    int row = blockIdx.x * 256 + threadIdx.x;
    const float* zp = z + (i64)row * 64;
    float zv[64]; float zz = 0.f;
#pragma unroll
    for (int d = 0; d < 64; d++) { float v = zp[d]; zv[d] = v; zz += v * v; }
    float best = 3.4e38f; int bk = 0;
    for (int h = 0; h < 4; h++) {
        __syncthreads();
        for (int i = threadIdx.x; i < 128 * 64; i += 256) Es[i] = E[(i64)h * 8192 + i];
        __syncthreads();
        for (int k = 0; k < 128; k++) {
            const float* e = Es + k * 64;
            float dot = 0.f;
#pragma unroll
            for (int d = 0; d < 64; d++) dot = fmaf(zv[d], e[d], dot);
            float dist = (zz + ee[h * 128 + k]) - 2.f * dot;
            if (dist < best) { best = dist; bk = h * 128 + k; }
        }
    }
    ki[row] = bk;
    const float* eb = E + (i64)bk * 64;
#pragma unroll
    for (int d = 0; d < 64; d++) zqf[(i64)row * 64 + d] = eb[d];
}

// =============== split-K GEMM ===============
__global__ __launch_bounds__(256)
void gemm_part_k(const float* __restrict__ A, const float* __restrict__ W,
                 float* __restrict__ part, int K, int N, int kchunk)
{
    __shared__ float As[128][17];
    __shared__ float Ws[16][64];
    const int n0 = blockIdx.x * 64;
    const int ks = blockIdx.y;
    const int kb0  = ks * kchunk;
    const int kend = min(K, kb0 + kchunk);
    const int tid = threadIdx.x;
    const int tn = tid & 15, tm = tid >> 4;
    float acc[8][4];
#pragma unroll
    for (int i = 0; i < 8; i++)
#pragma unroll
        for (int j = 0; j < 4; j++) acc[i][j] = 0.f;

    for (int kb = kb0; kb < kend; kb += 16) {
        __syncthreads();
        for (int i = tid; i < 2048; i += 256) {
            int m = i >> 4, kk = i & 15;
            int k = kb + kk;
            As[m][kk] = (k < kend) ? A[(i64)m * K + k] : 0.f;
        }
        for (int i = tid; i < 1024; i += 256) {
            int kk = i >> 6, nl = i & 63;
            int k = kb + kk, n = n0 + nl;
            Ws[kk][nl] = (k < kend && n < N) ? W[(i64)k * N + n] : 0.f;
        }
        __syncthreads();
#pragma unroll
        for (int kk = 0; kk < 16; kk++) {
            float av[8], wv[4];
#pragma unroll
            for (int i = 0; i < 8; i++) av[i] = As[tm * 8 + i][kk];
#pragma unroll
            for (int j = 0; j < 4; j++) wv[j] = Ws[kk][tn * 4 + j];
#pragma unroll
            for (int i = 0; i < 8; i++)
#pragma unroll
                for (int j = 0; j < 4; j++) acc[i][j] = fmaf(av[i], wv[j], acc[i][j]);
        }
    }
#pragma unroll
    for (int i = 0; i < 8; i++) {
        int m = tm * 8 + i;
#pragma unroll
        for (int j = 0; j < 4; j++) {
            int n = n0 + tn * 4 + j;
            if (n < N) part[((i64)ks * 128 + m) * N + n] = acc[i][j];
        }
    }
}

__global__ void combine_k(const float* __restrict__ part, const float* __restrict__ bias,
                          float* __restrict__ of, int MN, int N, int ksplit, int act)
{
    for (int i = blockIdx.x * blockDim.x + threadIdx.x; i < MN; i += gridDim.x * blockDim.x) {
        float s = 0.f;
        for (int t = 0; t < ksplit; t++) s += part[(i64)t * MN + i];
        s += bias[i % N];
        if (act == 1) s = s > 0.f ? s : 0.f;
        else if (act == 2) s = tanhf(s);
        of[i] = s;
    }
}

__global__ void blend_k(const float* __restrict__ q, const float* __restrict__ d,
                        const float* __restrict__ hu, int col, float* __restrict__ o,
                        int per_b, int total)
{
    for (int i = blockIdx.x * blockDim.x + threadIdx.x; i < total; i += gridDim.x * blockDim.x) {
        float u = hu[(i / per_b) * 2 + col];
        o[i] = u * q[i] + (1.f - u) * d[i];
    }
}

__global__ __launch_bounds__(256)
void value_k(const float* __restrict__ x, const float* __restrict__ w,
             const float* __restrict__ b, float* __restrict__ valf)
{
    int m = blockIdx.x;
    float s = 0.f;
    const float* xp = x + (i64)m * 11552;
    for (int k = threadIdx.x; k < 11552; k += 256) s = fmaf(xp[k], w[k], s);
    for (int o = 32; o > 0; o >>= 1) s += __shfl_down(s, o);
    __shared__ float r[4];
    int lane = threadIdx.x & 63, wid = threadIdx.x >> 6;
    if (lane == 0) r[wid] = s;
    __syncthreads();
    if (threadIdx.x == 0)
        valf[m] = tanhf(r[0] + r[1] + r[2] + r[3] + b[0]);
}

// =============== emit phase (d_out is FLOAT32) ===============
__global__ void emit_f32_k(const float* __restrict__ src, float* __restrict__ out, i64 off, int n)
{
    for (int i = blockIdx.x * blockDim.x + threadIdx.x; i < n; i += gridDim.x * blockDim.x)
        out[off + i] = src[i];
}

__global__ void emit_k_k(const int* __restrict__ ki, float* __restrict__ out, i64 off, int n)
{
    for (int i = blockIdx.x * blockDim.x + threadIdx.x; i < n; i += gridDim.x * blockDim.x)
        out[off + i] = (float)ki[i];
}

__global__ void emit_em_k(const float* __restrict__ cm, float* __restrict__ out, i64 off,
                          int D, int SPL, int total)
{
    for (int i = blockIdx.x * blockDim.x + threadIdx.x; i < total; i += gridDim.x * blockDim.x) {
        int c = (i / SPL) % D;
        out[off + i] = cm[c];
    }
}

// =============== guard markers ===============
__global__ void marker_k(float* __restrict__ out, int code)
{
    if (threadIdx.x < 64) out[threadIdx.x] = 3000.f + 100.f * code;
}

__global__ void sentinel_k(float* __restrict__ out)
{
    if (threadIdx.x < 128) out[OUT_VALUE + threadIdx.x] = 2000.0f;
}

// ===================== host launch =====================
extern "C" void kernel_launch(void* const* d_in, const int* in_sizes, int n_in,
                              void* d_out, int out_size, void* d_ws, size_t ws_size,
                              hipStream_t stream)
{
    float* out = (float*)d_out;

    int bad = -1;
    if (out_size != (int)OUT_TOTAL) bad = 0;
    else if (n_in != 41) bad = 1;
    else if (in_sizes[0] != 128 * 18 * 361) bad = 2;
    else if (in_sizes[21] != 11552 * 256) bad = 3;
    if (bad >= 0) { marker_k<<<1, 64, 0, stream>>>(out, bad); return; }

    const float* obs   = (const float*)d_in[0];
    const float* hier  = (const float*)d_in[1];
    const float* c0w   = (const float*)d_in[2];
    const float* bn0g  = (const float*)d_in[4];
    const float* bn0b  = (const float*)d_in[5];
    const float* rb1w  = (const float*)d_in[6];
    const float* rbn1g = (const float*)d_in[8];
    const float* rbn1b = (const float*)d_in[9];
    const float* rb2w  = (const float*)d_in[10];
    const float* rbn2g = (const float*)d_in[12];
    const float* rbn2b = (const float*)d_in[13];
    const float* c2w   = (const float*)d_in[14];
    const float* bn2g  = (const float*)d_in[16];
    const float* bn2b  = (const float*)d_in[17];
    const float* E0    = (const float*)d_in[18];
    const float* E1    = (const float*)d_in[19];
    const float* E2    = (const float*)d_in[20];
    const float* fc1w  = (const float*)d_in[21]; const float* fc1b  = (const float*)d_in[22];
    const float* fc2w  = (const float*)d_in[23]; const float* fc2b  = (const float*)d_in[24];
    const float* h2fw  = (const float*)d_in[25]; const float* h2fb  = (const float*)d_in[26];
    const float* h2f2w = (const float*)d_in[27]; const float* h2f2b = (const float*)d_in[28];
    const float* h2f3w = (const float*)d_in[29]; const float* h2f3b = (const float*)d_in[30];
    const float* h2f4w = (const float*)d_in[31]; const float* h2f4b = (const float*)d_in[32];
    const float* h1f3w = (const float*)d_in[33]; const float* h1f3b = (const float*)d_in[34];
    const float* h1f4w = (const float*)d_in[35]; const float* h1f4b = (const float*)d_in[36];
    const float* polw  = (const float*)d_in[37]; const float* polb  = (const float*)d_in[38];
    const float* valw  = (const float*)d_in[39]; const float* valb  = (const float*)d_in[40];

    float* wsf = (float*)d_ws;

    const size_t NEED_BYTES = (size_t)27860992 * 4;
    if (ws_size < NEED_BYTES) {
        sentinel_k<<<1, 128, 0, stream>>>(out);
        return;
    }

    float* scale = wsf + 0;        float* shift = wsf + 256;
    float* ee0 = wsf + 512;        float* ee1 = wsf + 1024;   float* ee2 = wsf + 1536;
    float* cm0 = wsf + 2048;       float* cm1 = wsf + 2112;   float* cm2 = wsf + 2176;
    int*   k0i = (int*)(wsf + 4096);
    int*   k1i = (int*)(wsf + 50304);
    int*   k2i = (int*)(wsf + 51328);
    float* h1a  = wsf + 53248;
    float* ze1f = wsf + 86016;
    float* zq1f = wsf + 151552;
    float* h2a  = wsf + 217088;
    float* ze2f = wsf + 233472;
    float* zq2f = wsf + 299008;
    float* h2b  = wsf + 364544;
    float* decf = wsf + 380928;
    float* x1f  = wsf + 446464;
    float* h1b  = wsf + 512000;
    float* polf = wsf + 544768;
    float* valf = wsf + 591104;

    float* A    = wsf + 655360;
    float* B    = wsf + 12484608;
    float* C64  = wsf + 24313856;
    float* WT   = wsf + 27271168;        // 589,824 floats (weight transpose)
    float* ze0f = A;
    float* zq0f = wsf + 655360 + 1572864;
    float* dec0 = wsf + 655360 + 3145728;
    float* xf   = wsf + 655360 + 4718592;
    float* part = B;

    const int TOT256 = 128 * 256 * 361;
    const int TOT32  = 128 * 32 * 361;
    const int TOT64  = 128 * 64 * 361;

    prep_k<<<4, 512, 0, stream>>>(E0, E1, E2, ee0, ee1, ee2, cm0, cm1, cm2);

    // ---- trunk (pipelined implicit-GEMM convs) ----
    wtr_k<<<64, 256, 0, stream>>>(c0w, WT, 256, 18);
    convgemm_k<18><<<dim3(361, 4), 256, 0, stream>>>(obs, WT, A, 256, 0, 256);
    bnstats_k<<<256, 256, 0, stream>>>(A, bn0g, bn0b, scale, shift, 256);
    bn_relu_k<<<1024, 256, 0, stream>>>(A, scale, shift, 256, TOT256);

    for (int i = 0; i < 3; i++) {
        wtr_k<<<576, 256, 0, stream>>>(rb1w + (i64)i * 589824, WT, 256, 256);
        convgemm_k<256><<<dim3(361, 4), 256, 0, stream>>>(A, WT, B, 256, 0, 256);
        bnstats_k<<<256, 256, 0, stream>>>(B, rbn1g + i * 256, rbn1b + i * 256, scale, shift, 256);
        bn_relu_k<<<1024, 256, 0, stream>>>(B, scale, shift, 256, TOT256);
        wtr_k<<<576, 256, 0, stream>>>(rb2w + (i64)i * 589824, WT, 256, 256);
        for (int c = 0; c < 4; c++) {
            convgemm_k<256><<<dim3(361, 1), 256, 0, stream>>>(B, WT, C64, 256, c * 64, 64);
            bnstats_k<<<64, 256, 0, stream>>>(C64, rbn2g + i * 256 + c * 64,
                                              rbn2b + i * 256 + c * 64, scale, shift, 64);
            bn_add_relu_slice_k<<<1024, 256, 0, stream>>>(A, C64, scale, shift, c * 64, TOT64);
        }
    }

    wtr_k<<<72, 256, 0, stream>>>(c2w, WT, 32, 256);
    convgemm_k<256><<<dim3(361, 1), 256, 0, stream>>>(A, WT, C64, 32, 0, 32);
    bnstats_k<<<32, 256, 0, stream>>>(C64, bn2g, bn2b, scale, shift, 32);
    bn_tanh_ws_k<<<1024, 256, 0, stream>>>(C64, scale, shift, ze0f, TOT32);

    vq0_k<<<181, 256, 0, stream>>>(ze0f, E0, ee0, zq0f, k0i);

    gemm_part_k<<<dim3(4, 32), 256, 0, stream>>>(ze0f, fc1w, part, 11552, 256, 361);
    combine_k<<<128, 256, 0, stream>>>(part, fc1b, h1a, 128 * 256, 256, 32, 1);
    gemm_part_k<<<dim3(8, 4), 256, 0, stream>>>(h1a, fc2w, part, 256, 512, 64);
    combine_k<<<256, 256, 0, stream>>>(part, fc2b, ze1f, 128 * 512, 512, 4, 2);
    vq64_k<<<4, 256, 0, stream>>>(ze1f, E1, ee1, zq1f, k1i);

    gemm_part_k<<<dim3(2, 8), 256, 0, stream>>>(ze1f, h2fw, part, 512, 128, 64);
    combine_k<<<64, 256, 0, stream>>>(part, h2fb, h2a, 128 * 128, 128, 8, 1);
    gemm_part_k<<<dim3(8, 2), 256, 0, stream>>>(h2a, h2f2w, part, 128, 512, 64);
    combine_k<<<256, 256, 0, stream>>>(part, h2f2b, ze2f, 128 * 512, 512, 2, 2);
    vq64_k<<<4, 256, 0, stream>>>(ze2f, E2, ee2, zq2f, k2i);

    gemm_part_k<<<dim3(2, 8), 256, 0, stream>>>(zq2f, h2f3w, part, 512, 128, 64);
    combine_k<<<64, 256, 0, stream>>>(part, h2f3b, h2b, 128 * 128, 128, 8, 1);
    gemm_part_k<<<dim3(8, 2), 256, 0, stream>>>(h2b, h2f4w, part, 128, 512, 64);
    combine_k<<<256, 256, 0, stream>>>(part, h2f4b, decf, 128 * 512, 512, 2, 2);
    blend_k<<<256, 256, 0, stream>>>(zq1f, decf, hier, 1, x1f, 512, 65536);

    gemm_part_k<<<dim3(4, 8), 256, 0, stream>>>(x1f, h1f3w, part, 512, 256, 64);
    combine_k<<<128, 256, 0, stream>>>(part, h1f3b, h1b, 128 * 256, 256, 8, 1);
    gemm_part_k<<<dim3(181, 2), 256, 0, stream>>>(h1b, h1f4w, part, 256, 11552, 128);
    combine_k<<<1024, 256, 0, stream>>>(part, h1f4b, dec0, TOT32, 11552, 2, 2);
    blend_k<<<1024, 256, 0, stream>>>(zq0f, dec0, hier, 0, xf, 11552, TOT32);

    gemm_part_k<<<dim3(6, 16), 256, 0, stream>>>(xf, polw, part, 11552, 362, 722);
    combine_k<<<256, 256, 0, stream>>>(part, polb, polf, 128 * 362, 362, 16, 0);
    value_k<<<128, 256, 0, stream>>>(xf, valw, valb, valf);

    // ---- emit phase: d_out is float32 ----
    emit_f32_k<<<128, 256, 0, stream>>>(polf, out, OUT_POLICY, 46336);
    emit_f32_k<<<1, 128, 0, stream>>>(valf, out, OUT_VALUE, 128);
    emit_f32_k<<<1024, 256, 0, stream>>>(ze0f, out, OUT_ZE0, TOT32);
    emit_f32_k<<<256, 256, 0, stream>>>(ze1f, out, OUT_ZE1, 65536);
    emit_f32_k<<<256, 256, 0, stream>>>(ze2f, out, OUT_ZE2, 65536);
    emit_f32_k<<<1024, 256, 0, stream>>>(zq0f, out, OUT_ZQ0, TOT32);
    emit_f32_k<<<256, 256, 0, stream>>>(zq1f, out, OUT_ZQ1, 65536);
    emit_f32_k<<<256, 256, 0, stream>>>(zq2f, out, OUT_ZQ2, 65536);
    emit_k_k<<<181, 256, 0, stream>>>(k0i, out, OUT_K0, 46208);
    emit_k_k<<<4, 256, 0, stream>>>(k1i, out, OUT_K1, 1024);
    emit_k_k<<<4, 256, 0, stream>>>(k2i, out, OUT_K2, 1024);
    emit_f32_k<<<1024, 256, 0, stream>>>(zq0f, out, OUT_ZQL0, TOT32);
    emit_f32_k<<<256, 256, 0, stream>>>(zq1f, out, OUT_ZQL1, 65536);
    emit_f32_k<<<256, 256, 0, stream>>>(zq2f, out, OUT_ZQL2, 65536);
    emit_em_k<<<1024, 256, 0, stream>>>(cm0, out, OUT_EM0, 32, 361, TOT32);
    emit_em_k<<<256, 256, 0, stream>>>(cm1, out, OUT_EM1, 64, 8, 65536);
    emit_em_k<<<256, 256, 0, stream>>>(cm2, out, OUT_EM2, 64, 8, 65536);
}

// Round 10
// 8749.351 us; speedup vs baseline: 2.6489x; 1.0762x over previous
//
#include <hip/hip_runtime.h>
#include <hip/hip_bf16.h>

typedef long long i64;

// ---- output element offsets (FLOAT32 elements — d_out is float*) ----
static constexpr i64 OUT_POLICY = 0;
static constexpr i64 OUT_VALUE  = 46336;
static constexpr i64 OUT_ZE0    = 46464;
static constexpr i64 OUT_ZE1    = 1525120;
static constexpr i64 OUT_ZE2    = 1590656;
static constexpr i64 OUT_ZQ0    = 1656192;
static constexpr i64 OUT_ZQ1    = 3134848;
static constexpr i64 OUT_ZQ2    = 3200384;
static constexpr i64 OUT_K0     = 3265920;
static constexpr i64 OUT_K1     = 3312128;
static constexpr i64 OUT_K2     = 3313152;
static constexpr i64 OUT_ZQL0   = 3314176;
static constexpr i64 OUT_ZQL1   = 4792832;
static constexpr i64 OUT_ZQL2   = 4858368;
static constexpr i64 OUT_EM0    = 4923904;
static constexpr i64 OUT_EM1    = 6402560;
static constexpr i64 OUT_EM2    = 6468096;
static constexpr i64 OUT_TOTAL  = 6533632;

// =============== weight transpose: w[co][ci][tap] -> wt[tap][ci][co] ===============
__global__ void wtr_k(const float* __restrict__ w, float* __restrict__ wt,
                      int COUT, int CIN)
{
    int total = COUT * CIN * 9;
    for (int idx = blockIdx.x * blockDim.x + threadIdx.x; idx < total;
         idx += gridDim.x * blockDim.x) {
        int co = idx / (CIN * 9);
        int r  = idx - co * CIN * 9;
        int ci = r / 9;
        int tap = r - ci * 9;
        wt[((i64)tap * CIN + ci) * COUT + co] = w[idx];
    }
}

// =============== conv 3x3 SAME as implicit GEMM, f32, software-pipelined ===============
// Block: 128 co x 128 cols, 256 threads, 8x8 per-thread tile.
// K = 9 taps x CIN, step 16. Double-buffered LDS; next step's globals prefetched
// into registers during current compute (T14).
template<int CIN>
__global__ __launch_bounds__(256)
void convgemm_k(const float* __restrict__ X,   // [128][CIN][361]
                const float* __restrict__ wt,  // [9][CIN][wtW]
                float* __restrict__ Y,         // [128][coutT][361]
                int wtW, int coW0, int coutT)
{
    constexpr int NCB = (CIN + 15) / 16;
    constexpr int NS  = 9 * NCB;
    __shared__ float Ws[2][16][128];
    __shared__ float Bs[2][16][128];
    const int tid  = threadIdx.x;
    const int col0 = blockIdx.x * 128;
    const int co0  = blockIdx.y * 128;
    const int tn = tid & 15;
    const int tm = (tid >> 4) & 15;

    // staging indices (fixed per thread)
    const int kkS  = tid >> 5;             // 0..7
    const int cS0  = (tid & 31) * 4;       // 0..124, step 4 (col/co group base)

    // per-staging-col info (4 consecutive cols)
    int n_[4], y_[4], x_[4];
    const float* Xb[4];
#pragma unroll
    for (int j = 0; j < 4; j++) {
        int colj = col0 + cS0 + j;
        int nj = colj / 361;
        int sj = colj - nj * 361;
        n_[j] = nj;
        y_[j] = sj / 19;
        x_[j] = sj - y_[j] * 19;
        Xb[j] = X + ((i64)nj * CIN) * 361 + sj;
    }

    float4 wA, wB, bA, bB;

#define STAGE(S)                                                               \
    {                                                                          \
        const int tap_ = (S) / NCB, cb_ = ((S) % NCB) * 16;                    \
        const int ky_ = tap_ / 3, kx_ = tap_ - ky_ * 3;                        \
        const int doff_ = (ky_ - 1) * 19 + (kx_ - 1);                          \
        const int ci0_ = cb_ + kkS, ci1_ = ci0_ + 8;                           \
        const float* wr_ = wt + ((i64)(tap_ * CIN) + ci0_) * wtW               \
                              + coW0 + co0 + cS0;                              \
        const bool wok_ = (coW0 + co0 + cS0) < wtW;                            \
        wA = (wok_ && ci0_ < CIN) ? *(const float4*)wr_                        \
                                  : float4{0.f, 0.f, 0.f, 0.f};                \
        wB = (wok_ && ci1_ < CIN) ? *(const float4*)(wr_ + (i64)8 * wtW)       \
                                  : float4{0.f, 0.f, 0.f, 0.f};                \
        bool v0_ = (y_[0]+ky_>=1)&(y_[0]+ky_<=19)&(x_[0]+kx_>=1)&(x_[0]+kx_<=19); \
        bool v1_ = (y_[1]+ky_>=1)&(y_[1]+ky_<=19)&(x_[1]+kx_>=1)&(x_[1]+kx_<=19); \
        bool v2_ = (y_[2]+ky_>=1)&(y_[2]+ky_<=19)&(x_[2]+kx_>=1)&(x_[2]+kx_<=19); \
        bool v3_ = (y_[3]+ky_>=1)&(y_[3]+ky_<=19)&(x_[3]+kx_>=1)&(x_[3]+kx_<=19); \
        bA.x = (v0_ && ci0_ < CIN) ? Xb[0][(i64)ci0_ * 361 + doff_] : 0.f;     \
        bA.y = (v1_ && ci0_ < CIN) ? Xb[1][(i64)ci0_ * 361 + doff_] : 0.f;     \
        bA.z = (v2_ && ci0_ < CIN) ? Xb[2][(i64)ci0_ * 361 + doff_] : 0.f;     \
        bA.w = (v3_ && ci0_ < CIN) ? Xb[3][(i64)ci0_ * 361 + doff_] : 0.f;     \
        bB.x = (v0_ && ci1_ < CIN) ? Xb[0][(i64)ci1_ * 361 + doff_] : 0.f;     \
        bB.y = (v1_ && ci1_ < CIN) ? Xb[1][(i64)ci1_ * 361 + doff_] : 0.f;     \
        bB.z = (v2_ && ci1_ < CIN) ? Xb[2][(i64)ci1_ * 361 + doff_] : 0.f;     \
        bB.w = (v3_ && ci1_ < CIN) ? Xb[3][(i64)ci1_ * 361 + doff_] : 0.f;     \
    }

#define WRITE(BUF)                                                             \
    {                                                                          \
        *(float4*)&Ws[BUF][kkS    ][cS0] = wA;                                 \
        *(float4*)&Ws[BUF][kkS + 8][cS0] = wB;                                 \
        *(float4*)&Bs[BUF][kkS    ][cS0] = bA;                                 \
        *(float4*)&Bs[BUF][kkS + 8][cS0] = bB;                                 \
    }

    float acc[8][8];
#pragma unroll
    for (int i = 0; i < 8; i++)
#pragma unroll
        for (int j = 0; j < 8; j++) acc[i][j] = 0.f;

    STAGE(0)
    WRITE(0)
    int cur = 0;
    for (int s = 0; s < NS; s++) {
        if (s + 1 < NS) STAGE(s + 1)          // globals in flight during compute
        __syncthreads();                       // buf[cur] ready
#pragma unroll
        for (int kk = 0; kk < 16; kk++) {
            const float4 w0 = *(const float4*)&Ws[cur][kk][tm * 4];
            const float4 w1 = *(const float4*)&Ws[cur][kk][tm * 4 + 64];
            const float4 b0 = *(const float4*)&Bs[cur][kk][tn * 4];
            const float4 b1 = *(const float4*)&Bs[cur][kk][tn * 4 + 64];
            float wv[8] = {w0.x, w0.y, w0.z, w0.w, w1.x, w1.y, w1.z, w1.w};
            float bv[8] = {b0.x, b0.y, b0.z, b0.w, b1.x, b1.y, b1.z, b1.w};
#pragma unroll
            for (int wi = 0; wi < 8; wi++)
#pragma unroll
                for (int bj = 0; bj < 8; bj++)
                    acc[wi][bj] = fmaf(wv[wi], bv[bj], acc[wi][bj]);
        }
        if (s + 1 < NS) WRITE(cur ^ 1)        // vmcnt wait lands here
        cur ^= 1;
    }
#undef STAGE
#undef WRITE

    // store
#pragma unroll
    for (int bj = 0; bj < 8; bj++) {
        int lc = (bj < 4) ? (tn * 4 + bj) : (64 + tn * 4 + bj - 4);
        int colT = col0 + lc;
        int nT = colT / 361;
        int sT = colT - nT * 361;
        float* yp = Y + ((i64)nT * coutT + co0) * 361 + sT;
#pragma unroll
        for (int wi = 0; wi < 8; wi++) {
            int co = (wi < 4) ? (tm * 4 + wi) : (64 + tm * 4 + wi - 4);
            if (co0 + co < coutT) yp[(i64)co * 361] = acc[wi][bj];
        }
    }
}

// =============== BN batch-stats -> scale/shift ===============
__global__ __launch_bounds__(256)
void bnstats_k(const float* __restrict__ x, const float* __restrict__ g,
               const float* __restrict__ b, float* __restrict__ scale,
               float* __restrict__ shift, int C)
{
    const int c = blockIdx.x;
    float s = 0.f, s2 = 0.f;
    for (int n = 0; n < 128; n++) {
        const float* p = x + ((i64)n * C + c) * 361;
        for (int i = threadIdx.x; i < 361; i += 256) {
            float v = p[i]; s += v; s2 += v * v;
        }
    }
    __shared__ float rs[4], rq[4];
    for (int o = 32; o > 0; o >>= 1) { s += __shfl_down(s, o); s2 += __shfl_down(s2, o); }
    int lane = threadIdx.x & 63, wid = threadIdx.x >> 6;
    if (lane == 0) { rs[wid] = s; rq[wid] = s2; }
    __syncthreads();
    if (threadIdx.x == 0) {
        float S = rs[0] + rs[1] + rs[2] + rs[3];
        float Q = rq[0] + rq[1] + rq[2] + rq[3];
        const float inv = 1.f / 46208.f;
        float m  = S * inv;
        float var = Q * inv - m * m;
        float sc = g[c] * rsqrtf(var + 1e-5f);
        scale[c] = sc;
        shift[c] = b[c] - m * sc;
    }
}

// =============== BN apply variants (ws-only) ===============
__global__ void bn_relu_k(float* __restrict__ x, const float* __restrict__ scale,
                          const float* __restrict__ shift, int C, int total)
{
    for (int i = blockIdx.x * blockDim.x + threadIdx.x; i < total; i += gridDim.x * blockDim.x) {
        int c = (i / 361) % C;
        float v = fmaf(x[i], scale[c], shift[c]);
        x[i] = v > 0.f ? v : 0.f;
    }
}

__global__ void bn_add_relu_full_k(float* __restrict__ xa, const float* __restrict__ xc,
                                   const float* __restrict__ scale, const float* __restrict__ shift,
                                   int C, int total)
{
    for (int i = blockIdx.x * blockDim.x + threadIdx.x; i < total; i += gridDim.x * blockDim.x) {
        int c = (i / 361) % C;
        float v = xa[i] + fmaf(xc[i], scale[c], shift[c]);
        xa[i] = v > 0.f ? v : 0.f;
    }
}

__global__ void bn_add_relu_slice_k(float* __restrict__ xa, const float* __restrict__ xc,
                                    const float* __restrict__ scale, const float* __restrict__ shift,
                                    int cbase, int total)
{
    for (int i = blockIdx.x * blockDim.x + threadIdx.x; i < total; i += gridDim.x * blockDim.x) {
        int s = i % 361;
        int t = i / 361;
        int ch = t % 64;
        int n = t / 64;
        i64 ai = ((i64)n * 256 + cbase + ch) * 361 + s;
        float v = xa[ai] + fmaf(xc[i], scale[ch], shift[ch]);
        xa[ai] = v > 0.f ? v : 0.f;
    }
}

__global__ void bn_tanh_ws_k(const float* __restrict__ x, const float* __restrict__ scale,
                             const float* __restrict__ shift, float* __restrict__ zf, int total)
{
    for (int i = blockIdx.x * blockDim.x + threadIdx.x; i < total; i += gridDim.x * blockDim.x) {
        int c = (i / 361) & 31;
        zf[i] = tanhf(fmaf(x[i], scale[c], shift[c]));
    }
}

// =============== codebook prep ===============
__global__ void prep_k(const float* __restrict__ E0, const float* __restrict__ E1,
                       const float* __restrict__ E2,
                       float* __restrict__ ee0, float* __restrict__ ee1, float* __restrict__ ee2,
                       float* __restrict__ cm0, float* __restrict__ cm1, float* __restrict__ cm2)
{
    int t = threadIdx.x;
    if (blockIdx.x == 0) {
        float s = 0.f; const float* e = E0 + (i64)t * 32;
        for (int d = 0; d < 32; d++) s += e[d] * e[d];
        ee0[t] = s;
    } else if (blockIdx.x == 1) {
        float s = 0.f; const float* e = E1 + (i64)t * 64;
        for (int d = 0; d < 64; d++) s += e[d] * e[d];
        ee1[t] = s;
    } else if (blockIdx.x == 2) {
        float s = 0.f; const float* e = E2 + (i64)t * 64;
        for (int d = 0; d < 64; d++) s += e[d] * e[d];
        ee2[t] = s;
    } else {
        if (t < 32) {
            float s = 0.f; for (int k = 0; k < 512; k++) s += E0[k * 32 + t];
            cm0[t] = s * (1.f / 512.f);
        } else if (t >= 64 && t < 128) {
            int d = t - 64; float s = 0.f; for (int k = 0; k < 512; k++) s += E1[k * 64 + d];
            cm1[d] = s * (1.f / 512.f);
        } else if (t >= 128 && t < 192) {
            int d = t - 128; float s = 0.f; for (int k = 0; k < 512; k++) s += E2[k * 64 + d];
            cm2[d] = s * (1.f / 512.f);
        }
    }
}

// =============== VQ kernels (32 KB LDS, multi-pass staging) ===============
__global__ __launch_bounds__(256)
void vq0_k(const float* __restrict__ z, const float* __restrict__ E,
           const float* __restrict__ ee, float* __restrict__ zqf, int* __restrict__ ki)
{
    __shared__ float Es[256 * 32];
    int row = blockIdx.x * 256 + threadIdx.x;
    const bool live = row < 46208;
    const float* zp = z + (i64)(live ? row : 0) * 32;
    float zv[32]; float zz = 0.f;
#pragma unroll
    for (int d = 0; d < 32; d++) { float v = zp[d]; zv[d] = v; zz += v * v; }
    float best = 3.4e38f; int bk = 0;
    for (int h = 0; h < 2; h++) {
        __syncthreads();
        for (int i = threadIdx.x; i < 256 * 32; i += 256) Es[i] = E[h * 8192 + i];
        __syncthreads();
        for (int k = 0; k < 256; k++) {
            const float* e = Es + k * 32;
            float dot = 0.f;
#pragma unroll
            for (int d = 0; d < 32; d++) dot = fmaf(zv[d], e[d], dot);
            float dist = (zz + ee[h * 256 + k]) - 2.f * dot;
            if (dist < best) { best = dist; bk = h * 256 + k; }
        }
    }
    if (live) {
        ki[row] = bk;
        const float* eb = E + (i64)bk * 32;
#pragma unroll
        for (int d = 0; d < 32; d++) zqf[(i64)row * 32 + d] = eb[d];
    }
}

__global__ __launch_bounds__(256)
void vq64_k(const float* __restrict__ z, const float* __restrict__ E,
            const float* __restrict__ ee, float* __restrict__ zqf, int* __restrict__ ki)
{
    __shared__ float Es[128 * 64];
    int row = blockIdx.x * 256 + threadIdx.x;
    const float* zp = z + (i64)row * 64;
    float zv[64]; float zz = 0.f;
#pragma unroll
    for (int d = 0; d < 64; d++) { float v = zp[d]; zv[d] = v; zz += v * v; }
    float best = 3.4e38f; int bk = 0;
    for (int h = 0; h < 4; h++) {
        __syncthreads();
        for (int i = threadIdx.x; i < 128 * 64; i += 256) Es[i] = E[(i64)h * 8192 + i];
        __syncthreads();
        for (int k = 0; k < 128; k++) {
            const float* e = Es + k * 64;
            float dot = 0.f;
#pragma unroll
            for (int d = 0; d < 64; d++) dot = fmaf(zv[d], e[d], dot);
            float dist = (zz + ee[h * 128 + k]) - 2.f * dot;
            if (dist < best) { best = dist; bk = h * 128 + k; }
        }
    }
    ki[row] = bk;
    const float* eb = E + (i64)bk * 64;
#pragma unroll
    for (int d = 0; d < 64; d++) zqf[(i64)row * 64 + d] = eb[d];
}

// =============== split-K GEMM ===============
__global__ __launch_bounds__(256)
void gemm_part_k(const float* __restrict__ A, const float* __restrict__ W,
                 float* __restrict__ part, int K, int N, int kchunk)
{
    __shared__ float As[128][17];
    __shared__ float Ws[16][64];
    const int n0 = blockIdx.x * 64;
    const int ks = blockIdx.y;
    const int kb0  = ks * kchunk;
    const int kend = min(K, kb0 + kchunk);
    const int tid = threadIdx.x;
    const int tn = tid & 15, tm = tid >> 4;
    float acc[8][4];
#pragma unroll
    for (int i = 0; i < 8; i++)
#pragma unroll
        for (int j = 0; j < 4; j++) acc[i][j] = 0.f;

    for (int kb = kb0; kb < kend; kb += 16) {
        __syncthreads();
        for (int i = tid; i < 2048; i += 256) {
            int m = i >> 4, kk = i & 15;
            int k = kb + kk;
            As[m][kk] = (k < kend) ? A[(i64)m * K + k] : 0.f;
        }
        for (int i = tid; i < 1024; i += 256) {
            int kk = i >> 6, nl = i & 63;
            int k = kb + kk, n = n0 + nl;
            Ws[kk][nl] = (k < kend && n < N) ? W[(i64)k * N + n] : 0.f;
        }
        __syncthreads();
#pragma unroll
        for (int kk = 0; kk < 16; kk++) {
            float av[8], wv[4];
#pragma unroll
            for (int i = 0; i < 8; i++) av[i] = As[tm * 8 + i][kk];
#pragma unroll
            for (int j = 0; j < 4; j++) wv[j] = Ws[kk][tn * 4 + j];
#pragma unroll
            for (int i = 0; i < 8; i++)
#pragma unroll
                for (int j = 0; j < 4; j++) acc[i][j] = fmaf(av[i], wv[j], acc[i][j]);
        }
    }
#pragma unroll
    for (int i = 0; i < 8; i++) {
        int m = tm * 8 + i;
#pragma unroll
        for (int j = 0; j < 4; j++) {
            int n = n0 + tn * 4 + j;
            if (n < N) part[((i64)ks * 128 + m) * N + n] = acc[i][j];
        }
    }
}

__global__ void combine_k(const float* __restrict__ part, const float* __restrict__ bias,
                          float* __restrict__ of, int MN, int N, int ksplit, int act)
{
    for (int i = blockIdx.x * blockDim.x + threadIdx.x; i < MN; i += gridDim.x * blockDim.x) {
        float s = 0.f;
        for (int t = 0; t < ksplit; t++) s += part[(i64)t * MN + i];
        s += bias[i % N];
        if (act == 1) s = s > 0.f ? s : 0.f;
        else if (act == 2) s = tanhf(s);
        of[i] = s;
    }
}

__global__ void blend_k(const float* __restrict__ q, const float* __restrict__ d,
                        const float* __restrict__ hu, int col, float* __restrict__ o,
                        int per_b, int total)
{
    for (int i = blockIdx.x * blockDim.x + threadIdx.x; i < total; i += gridDim.x * blockDim.x) {
        float u = hu[(i / per_b) * 2 + col];
        o[i] = u * q[i] + (1.f - u) * d[i];
    }
}

__global__ __launch_bounds__(256)
void value_k(const float* __restrict__ x, const float* __restrict__ w,
             const float* __restrict__ b, float* __restrict__ valf)
{
    int m = blockIdx.x;
    float s = 0.f;
    const float* xp = x + (i64)m * 11552;
    for (int k = threadIdx.x; k < 11552; k += 256) s = fmaf(xp[k], w[k], s);
    for (int o = 32; o > 0; o >>= 1) s += __shfl_down(s, o);
    __shared__ float r[4];
    int lane = threadIdx.x & 63, wid = threadIdx.x >> 6;
    if (lane == 0) r[wid] = s;
    __syncthreads();
    if (threadIdx.x == 0)
        valf[m] = tanhf(r[0] + r[1] + r[2] + r[3] + b[0]);
}

// =============== emit phase (d_out is FLOAT32) ===============
__global__ void emit_f32_k(const float* __restrict__ src, float* __restrict__ out, i64 off, int n)
{
    for (int i = blockIdx.x * blockDim.x + threadIdx.x; i < n; i += gridDim.x * blockDim.x)
        out[off + i] = src[i];
}

__global__ void emit_k_k(const int* __restrict__ ki, float* __restrict__ out, i64 off, int n)
{
    for (int i = blockIdx.x * blockDim.x + threadIdx.x; i < n; i += gridDim.x * blockDim.x)
        out[off + i] = (float)ki[i];
}

__global__ void emit_em_k(const float* __restrict__ cm, float* __restrict__ out, i64 off,
                          int D, int SPL, int total)
{
    for (int i = blockIdx.x * blockDim.x + threadIdx.x; i < total; i += gridDim.x * blockDim.x) {
        int c = (i / SPL) % D;
        out[off + i] = cm[c];
    }
}

// =============== guard markers ===============
__global__ void marker_k(float* __restrict__ out, int code)
{
    if (threadIdx.x < 64) out[threadIdx.x] = 3000.f + 100.f * code;
}

__global__ void sentinel_k(float* __restrict__ out)
{
    if (threadIdx.x < 128) out[OUT_VALUE + threadIdx.x] = 2000.0f;
}

// ===================== host launch =====================
extern "C" void kernel_launch(void* const* d_in, const int* in_sizes, int n_in,
                              void* d_out, int out_size, void* d_ws, size_t ws_size,
                              hipStream_t stream)
{
    float* out = (float*)d_out;

    int bad = -1;
    if (out_size != (int)OUT_TOTAL) bad = 0;
    else if (n_in != 41) bad = 1;
    else if (in_sizes[0] != 128 * 18 * 361) bad = 2;
    else if (in_sizes[21] != 11552 * 256) bad = 3;
    if (bad >= 0) { marker_k<<<1, 64, 0, stream>>>(out, bad); return; }

    const float* obs   = (const float*)d_in[0];
    const float* hier  = (const float*)d_in[1];
    const float* c0w   = (const float*)d_in[2];
    const float* bn0g  = (const float*)d_in[4];
    const float* bn0b  = (const float*)d_in[5];
    const float* rb1w  = (const float*)d_in[6];
    const float* rbn1g = (const float*)d_in[8];
    const float* rbn1b = (const float*)d_in[9];
    const float* rb2w  = (const float*)d_in[10];
    const float* rbn2g = (const float*)d_in[12];
    const float* rbn2b = (const float*)d_in[13];
    const float* c2w   = (const float*)d_in[14];
    const float* bn2g  = (const float*)d_in[16];
    const float* bn2b  = (const float*)d_in[17];
    const float* E0    = (const float*)d_in[18];
    const float* E1    = (const float*)d_in[19];
    const float* E2    = (const float*)d_in[20];
    const float* fc1w  = (const float*)d_in[21]; const float* fc1b  = (const float*)d_in[22];
    const float* fc2w  = (const float*)d_in[23]; const float* fc2b  = (const float*)d_in[24];
    const float* h2fw  = (const float*)d_in[25]; const float* h2fb  = (const float*)d_in[26];
    const float* h2f2w = (const float*)d_in[27]; const float* h2f2b = (const float*)d_in[28];
    const float* h2f3w = (const float*)d_in[29]; const float* h2f3b = (const float*)d_in[30];
    const float* h2f4w = (const float*)d_in[31]; const float* h2f4b = (const float*)d_in[32];
    const float* h1f3w = (const float*)d_in[33]; const float* h1f3b = (const float*)d_in[34];
    const float* h1f4w = (const float*)d_in[35]; const float* h1f4b = (const float*)d_in[36];
    const float* polw  = (const float*)d_in[37]; const float* polb  = (const float*)d_in[38];
    const float* valw  = (const float*)d_in[39]; const float* valb  = (const float*)d_in[40];

    float* wsf = (float*)d_ws;

    // Path A: full-width rb2 scratch (C256) -> 146.9 MB. Path C fallback -> 111.4 MB.
    const size_t NEED_A = (size_t)36732928 * 4;
    const size_t NEED_C = (size_t)27860992 * 4;
    if (ws_size < NEED_C) {
        sentinel_k<<<1, 128, 0, stream>>>(out);
        return;
    }
    const bool fullC = (ws_size >= NEED_A);

    float* scale = wsf + 0;        float* shift = wsf + 256;
    float* ee0 = wsf + 512;        float* ee1 = wsf + 1024;   float* ee2 = wsf + 1536;
    float* cm0 = wsf + 2048;       float* cm1 = wsf + 2112;   float* cm2 = wsf + 2176;
    int*   k0i = (int*)(wsf + 4096);
    int*   k1i = (int*)(wsf + 50304);
    int*   k2i = (int*)(wsf + 51328);
    float* h1a  = wsf + 53248;
    float* ze1f = wsf + 86016;
    float* zq1f = wsf + 151552;
    float* h2a  = wsf + 217088;
    float* ze2f = wsf + 233472;
    float* zq2f = wsf + 299008;
    float* h2b  = wsf + 364544;
    float* decf = wsf + 380928;
    float* x1f  = wsf + 446464;
    float* h1b  = wsf + 512000;
    float* polf = wsf + 544768;
    float* valf = wsf + 591104;

    float* A    = wsf + 655360;
    float* B    = wsf + 12484608;
    float* C    = wsf + 24313856;                         // C256 (A-path) or C64 (C-path)
    float* WT   = fullC ? (wsf + 36143104) : (wsf + 27271168);
    float* ze0f = A;
    float* zq0f = wsf + 655360 + 1572864;
    float* dec0 = wsf + 655360 + 3145728;
    float* xf   = wsf + 655360 + 4718592;
    float* part = B;

    const int TOT256 = 128 * 256 * 361;
    const int TOT32  = 128 * 32 * 361;
    const int TOT64  = 128 * 64 * 361;

    prep_k<<<4, 512, 0, stream>>>(E0, E1, E2, ee0, ee1, ee2, cm0, cm1, cm2);

    // ---- trunk (pipelined implicit-GEMM convs, 128x128 tiles) ----
    wtr_k<<<64, 256, 0, stream>>>(c0w, WT, 256, 18);
    convgemm_k<18><<<dim3(361, 2), 256, 0, stream>>>(obs, WT, A, 256, 0, 256);
    bnstats_k<<<256, 256, 0, stream>>>(A, bn0g, bn0b, scale, shift, 256);
    bn_relu_k<<<1024, 256, 0, stream>>>(A, scale, shift, 256, TOT256);

    for (int i = 0; i < 3; i++) {
        wtr_k<<<576, 256, 0, stream>>>(rb1w + (i64)i * 589824, WT, 256, 256);
        convgemm_k<256><<<dim3(361, 2), 256, 0, stream>>>(A, WT, B, 256, 0, 256);
        bnstats_k<<<256, 256, 0, stream>>>(B, rbn1g + i * 256, rbn1b + i * 256, scale, shift, 256);
        bn_relu_k<<<1024, 256, 0, stream>>>(B, scale, shift, 256, TOT256);
        wtr_k<<<576, 256, 0, stream>>>(rb2w + (i64)i * 589824, WT, 256, 256);
        if (fullC) {
            convgemm_k<256><<<dim3(361, 2), 256, 0, stream>>>(B, WT, C, 256, 0, 256);
            bnstats_k<<<256, 256, 0, stream>>>(C, rbn2g + i * 256, rbn2b + i * 256, scale, shift, 256);
            bn_add_relu_full_k<<<1024, 256, 0, stream>>>(A, C, scale, shift, 256, TOT256);
        } else {
            for (int c = 0; c < 4; c++) {
                convgemm_k<256><<<dim3(361, 1), 256, 0, stream>>>(B, WT, C, 256, c * 64, 64);
                bnstats_k<<<64, 256, 0, stream>>>(C, rbn2g + i * 256 + c * 64,
                                                  rbn2b + i * 256 + c * 64, scale, shift, 64);
                bn_add_relu_slice_k<<<1024, 256, 0, stream>>>(A, C, scale, shift, c * 64, TOT64);
            }
        }
    }

    wtr_k<<<72, 256, 0, stream>>>(c2w, WT, 32, 256);
    convgemm_k<256><<<dim3(361, 1), 256, 0, stream>>>(A, WT, C, 32, 0, 32);
    bnstats_k<<<32, 256, 0, stream>>>(C, bn2g, bn2b, scale, shift, 32);
    bn_tanh_ws_k<<<1024, 256, 0, stream>>>(C, scale, shift, ze0f, TOT32);

    vq0_k<<<181, 256, 0, stream>>>(ze0f, E0, ee0, zq0f, k0i);

    gemm_part_k<<<dim3(4, 32), 256, 0, stream>>>(ze0f, fc1w, part, 11552, 256, 361);
    combine_k<<<128, 256, 0, stream>>>(part, fc1b, h1a, 128 * 256, 256, 32, 1);
    gemm_part_k<<<dim3(8, 4), 256, 0, stream>>>(h1a, fc2w, part, 256, 512, 64);
    combine_k<<<256, 256, 0, stream>>>(part, fc2b, ze1f, 128 * 512, 512, 4, 2);
    vq64_k<<<4, 256, 0, stream>>>(ze1f, E1, ee1, zq1f, k1i);

    gemm_part_k<<<dim3(2, 8), 256, 0, stream>>>(ze1f, h2fw, part, 512, 128, 64);
    combine_k<<<64, 256, 0, stream>>>(part, h2fb, h2a, 128 * 128, 128, 8, 1);
    gemm_part_k<<<dim3(8, 2), 256, 0, stream>>>(h2a, h2f2w, part, 128, 512, 64);
    combine_k<<<256, 256, 0, stream>>>(part, h2f2b, ze2f, 128 * 512, 512, 2, 2);
    vq64_k<<<4, 256, 0, stream>>>(ze2f, E2, ee2, zq2f, k2i);

    gemm_part_k<<<dim3(2, 8), 256, 0, stream>>>(zq2f, h2f3w, part, 512, 128, 64);
    combine_k<<<64, 256, 0, stream>>>(part, h2f3b, h2b, 128 * 128, 128, 8, 1);
    gemm_part_k<<<dim3(8, 2), 256, 0, stream>>>(h2b, h2f4w, part, 128, 512, 64);
    combine_k<<<256, 256, 0, stream>>>(part, h2f4b, decf, 128 * 512, 512, 2, 2);
    blend_k<<<256, 256, 0, stream>>>(zq1f, decf, hier, 1, x1f, 512, 65536);

    gemm_part_k<<<dim3(4, 8), 256, 0, stream>>>(x1f, h1f3w, part, 512, 256, 64);
    combine_k<<<128, 256, 0, stream>>>(part, h1f3b, h1b, 128 * 256, 256, 8, 1);
    gemm_part_k<<<dim3(181, 2), 256, 0, stream>>>(h1b, h1f4w, part, 256, 11552, 128);
    combine_k<<<1024, 256, 0, stream>>>(part, h1f4b, dec0, TOT32, 11552, 2, 2);
    blend_k<<<1024, 256, 0, stream>>>(zq0f, dec0, hier, 0, xf, 11552, TOT32);

    gemm_part_k<<<dim3(6, 16), 256, 0, stream>>>(xf, polw, part, 11552, 362, 722);
    combine_k<<<256, 256, 0, stream>>>(part, polb, polf, 128 * 362, 362, 16, 0);
    value_k<<<128, 256, 0, stream>>>(xf, valw, valb, valf);

    // ---- emit phase: d_out is float32 ----
    emit_f32_k<<<128, 256, 0, stream>>>(polf, out, OUT_POLICY, 46336);
    emit_f32_k<<<1, 128, 0, stream>>>(valf, out, OUT_VALUE, 128);
    emit_f32_k<<<1024, 256, 0, stream>>>(ze0f, out, OUT_ZE0, TOT32);
    emit_f32_k<<<256, 256, 0, stream>>>(ze1f, out, OUT_ZE1, 65536);
    emit_f32_k<<<256, 256, 0, stream>>>(ze2f, out, OUT_ZE2, 65536);
    emit_f32_k<<<1024, 256, 0, stream>>>(zq0f, out, OUT_ZQ0, TOT32);
    emit_f32_k<<<256, 256, 0, stream>>>(zq1f, out, OUT_ZQ1, 65536);
    emit_f32_k<<<256, 256, 0, stream>>>(zq2f, out, OUT_ZQ2, 65536);
    emit_k_k<<<181, 256, 0, stream>>>(k0i, out, OUT_K0, 46208);
    emit_k_k<<<4, 256, 0, stream>>>(k1i, out, OUT_K1, 1024);
    emit_k_k<<<4, 256, 0, stream>>>(k2i, out, OUT_K2, 1024);
    emit_f32_k<<<1024, 256, 0, stream>>>(zq0f, out, OUT_ZQL0, TOT32);
    emit_f32_k<<<256, 256, 0, stream>>>(zq1f, out, OUT_ZQL1, 65536);
    emit_f32_k<<<256, 256, 0, stream>>>(zq2f, out, OUT_ZQL2, 65536);
    emit_em_k<<<1024, 256, 0, stream>>>(cm0, out, OUT_EM0, 32, 361, TOT32);
    emit_em_k<<<256, 256, 0, stream>>>(cm1, out, OUT_EM1, 64, 8, 65536);
    emit_em_k<<<256, 256, 0, stream>>>(cm2, out, OUT_EM2, 64, 8, 65536);
}

// Round 11
// 3365.073 us; speedup vs baseline: 6.8873x; 2.6000x over previous
//
#include <hip/hip_runtime.h>
#include <hip/hip_bf16.h>

typedef long long i64;
typedef __attribute__((ext_vector_type(8))) short bf16x8;
typedef __attribute__((ext_vector_type(4))) float f32x4;

// ---- output element offsets (FLOAT32 elements — d_out is float*) ----
static constexpr i64 OUT_POLICY = 0;
static constexpr i64 OUT_VALUE  = 46336;
static constexpr i64 OUT_ZE0    = 46464;
static constexpr i64 OUT_ZE1    = 1525120;
static constexpr i64 OUT_ZE2    = 1590656;
static constexpr i64 OUT_ZQ0    = 1656192;
static constexpr i64 OUT_ZQ1    = 3134848;
static constexpr i64 OUT_ZQ2    = 3200384;
static constexpr i64 OUT_K0     = 3265920;
static constexpr i64 OUT_K1     = 3312128;
static constexpr i64 OUT_K2     = 3313152;
static constexpr i64 OUT_ZQL0   = 3314176;
static constexpr i64 OUT_ZQL1   = 4792832;
static constexpr i64 OUT_ZQL2   = 4858368;
static constexpr i64 OUT_EM0    = 4923904;
static constexpr i64 OUT_EM1    = 6402560;
static constexpr i64 OUT_EM2    = 6468096;
static constexpr i64 OUT_TOTAL  = 6533632;

__device__ __forceinline__ short bf16_hi(float v, float* back)
{
    unsigned b = __float_as_uint(v);
    unsigned hb = (b + 0x8000u) & 0xFFFF0000u;
    *back = __uint_as_float(hb);
    return (short)(hb >> 16);
}
__device__ __forceinline__ short bf16_of(float v)
{
    return (short)((__float_as_uint(v) + 0x8000u) >> 16);
}

// =============== weight transpose (f32 path): w[co][ci][tap] -> wt[tap][ci][co] ======
__global__ void wtr_k(const float* __restrict__ w, float* __restrict__ wt,
                      int COUT, int CIN)
{
    int total = COUT * CIN * 9;
    for (int idx = blockIdx.x * blockDim.x + threadIdx.x; idx < total;
         idx += gridDim.x * blockDim.x) {
        int co = idx / (CIN * 9);
        int r  = idx - co * CIN * 9;
        int ci = r / 9;
        int tap = r - ci * 9;
        wt[((i64)tap * CIN + ci) * COUT + co] = w[idx];
    }
}

// =============== MFMA weight prep: swizzled bf16 hi/lo tiles ===============
// WT4 layout: tile T = s*2 + ct  (s = c*9 + t), each tile 8192 shorts =
// [128 co_l][64 k2] with byte-swizzle (slot ^= row&7), k2<32: hi(ci), k2>=32: lo(ci).
__global__ void wtr4_k(const float* __restrict__ w, short* __restrict__ wt4,
                       int CIN, int COUT)
{
    int NC = CIN / 32;
    int total = NC * 9 * 2 * 8192;
    for (int idx = blockIdx.x * blockDim.x + threadIdx.x; idx < total;
         idx += gridDim.x * blockDim.x) {
        int tile = idx >> 13;
        int pos  = idx & 8191;
        int row   = pos >> 6;           // co_l
        int sslot = (pos >> 3) & 7;     // physical 16B slot
        int r     = pos & 7;
        int slot  = sslot ^ (row & 7);  // logical slot (involution)
        int k2    = slot * 8 + r;
        int ct = tile & 1;
        int s  = tile >> 1;
        int c  = s / 9, t = s - c * 9;
        int co = ct * 128 + row;
        int ci = c * 32 + (k2 & 31);
        short outv = 0;
        if (co < COUT) {
            float v = w[((i64)co * CIN + ci) * 9 + t];
            float hf;
            short hs = bf16_hi(v, &hf);
            outv = (k2 < 32) ? hs : bf16_of(v - hf);
        }
        wt4[idx] = outv;
    }
}

// =============== MFMA conv 3x3: implicit GEMM, 4-term bf16 split ===============
// Block 256 thr (4 waves), tile 128co x 128sp; wave = 64co x 64sp (4x4 16x16 frags).
// Chunk = 32 ci; k2 rows [hi(32)|lo(32)] in 128B swizzled LDS rows.
template<int CIN>
__global__ __launch_bounds__(256)
void convmfma_k(const float* __restrict__ X, const short* __restrict__ WT4,
                float* __restrict__ Y, int coutT)
{
    constexpr int NC = CIN / 32;
    constexpr int NS = NC * 9;
    __shared__ short At[2][8192];
    __shared__ short Bt[2][8192];
    const int tid  = threadIdx.x;
    const int lane = tid & 63;
    const int w    = tid >> 6;
    const int wco  = (w & 1) * 64;
    const int wsp  = (w >> 1) * 64;
    const int col0 = blockIdx.x * 128;
    const int ct   = blockIdx.y;
    const int co0  = ct * 128;

    // B staging identity
    const int spS = tid & 127;
    const int cig = tid >> 7;           // 0/1 -> ci sub-block of 16
    const int colS = col0 + spS;
    const int nS = colS / 361;
    const int sS = colS - nS * 361;
    const int yS = sS / 19, xS = sS - yS * 19;
    const float* Xb = X + (i64)nS * CIN * 361 + sS;

    float xv[16];

#define A_ISSUE(BUF, S)                                                         \
    {                                                                           \
        const short* gp0 = WT4 + ((i64)((S) * 2 + ct) << 13) + (w << 11) + (lane << 3); \
        short* lp0 = &At[BUF][(w << 11)];                                       \
        __builtin_amdgcn_global_load_lds(gp0,        lp0,        16, 0, 0);     \
        __builtin_amdgcn_global_load_lds(gp0 + 512,  lp0 + 512,  16, 0, 0);     \
        __builtin_amdgcn_global_load_lds(gp0 + 1024, lp0 + 1024, 16, 0, 0);     \
        __builtin_amdgcn_global_load_lds(gp0 + 1536, lp0 + 1536, 16, 0, 0);     \
    }

#define B_LOAD(S)                                                               \
    {                                                                           \
        const int c_ = (S) / 9, t_ = (S) - c_ * 9;                              \
        const int ky_ = t_ / 3, kx_ = t_ - ky_ * 3;                             \
        const bool v_ = (yS + ky_ >= 1) & (yS + ky_ <= 19) &                    \
                        (xS + kx_ >= 1) & (xS + kx_ <= 19);                     \
        const float* xp_ = Xb + (i64)(c_ * 32 + cig * 16) * 361                 \
                              + (ky_ - 1) * 19 + (kx_ - 1);                     \
        _Pragma("unroll")                                                       \
        for (int j = 0; j < 16; j++) xv[j] = v_ ? xp_[(i64)j * 361] : 0.f;      \
    }

#define B_WRITE(BUF)                                                            \
    {                                                                           \
        bf16x8 h0, h1, l0, l1;                                                  \
        _Pragma("unroll")                                                       \
        for (int j = 0; j < 8; j++) {                                           \
            float hf;                                                           \
            short hs = bf16_hi(xv[j], &hf);                                     \
            h0[j] = hs; l0[j] = bf16_of(xv[j] - hf);                            \
        }                                                                       \
        _Pragma("unroll")                                                       \
        for (int j = 0; j < 8; j++) {                                           \
            float hf;                                                           \
            short hs = bf16_hi(xv[8 + j], &hf);                                 \
            h1[j] = hs; l1[j] = bf16_of(xv[8 + j] - hf);                        \
        }                                                                       \
        short* bp = &Bt[BUF][spS << 6];                                         \
        const int sw = spS & 7;                                                 \
        *(bf16x8*)(bp + (((cig * 2 + 0) ^ sw) << 3)) = h0;                      \
        *(bf16x8*)(bp + (((cig * 2 + 1) ^ sw) << 3)) = h1;                      \
        *(bf16x8*)(bp + (((4 + cig * 2 + 0) ^ sw) << 3)) = l0;                  \
        *(bf16x8*)(bp + (((4 + cig * 2 + 1) ^ sw) << 3)) = l1;                  \
    }

    f32x4 acc[4][4];
#pragma unroll
    for (int i = 0; i < 4; i++)
#pragma unroll
        for (int j = 0; j < 4; j++) acc[i][j] = (f32x4){0.f, 0.f, 0.f, 0.f};

    A_ISSUE(0, 0)
    B_LOAD(0)
    B_WRITE(0)
    int cur = 0;
    for (int s = 0; s < NS; s++) {
        __syncthreads();                 // buf[cur] ready (vmcnt+ds drained)
        if (s + 1 < NS) { A_ISSUE(cur ^ 1, s + 1) B_LOAD(s + 1) }
        {
            bf16x8 bfr[2][4];
#pragma unroll
            for (int hb = 0; hb < 2; hb++)
#pragma unroll
                for (int fb = 0; fb < 4; fb++) {
                    int row = wsp + fb * 16 + (lane & 15);
                    int slot = hb * 4 + (lane >> 4);
                    bfr[hb][fb] = *(const bf16x8*)&Bt[cur][(row << 6) + (((slot ^ (row & 7))) << 3)];
                }
#pragma unroll
            for (int ha = 0; ha < 2; ha++)
#pragma unroll
                for (int fa = 0; fa < 4; fa++) {
                    int row = wco + fa * 16 + (lane & 15);
                    int slot = ha * 4 + (lane >> 4);
                    bf16x8 af = *(const bf16x8*)&At[cur][(row << 6) + (((slot ^ (row & 7))) << 3)];
#pragma unroll
                    for (int hb = 0; hb < 2; hb++)
#pragma unroll
                        for (int fb = 0; fb < 4; fb++)
                            acc[fa][fb] = __builtin_amdgcn_mfma_f32_16x16x32_bf16(
                                af, bfr[hb][fb], acc[fa][fb], 0, 0, 0);
                }
        }
        if (s + 1 < NS) B_WRITE(cur ^ 1)
        cur ^= 1;
    }
#undef A_ISSUE
#undef B_LOAD
#undef B_WRITE

    // store: D[m=(l>>4)*4+r][n=l&15] per frag
#pragma unroll
    for (int fb = 0; fb < 4; fb++) {
        int col = col0 + wsp + fb * 16 + (lane & 15);
        int nT = col / 361, sT = col - nT * 361;
        float* yp = Y + ((i64)nT * coutT + co0 + wco) * 361 + sT;
#pragma unroll
        for (int fa = 0; fa < 4; fa++)
#pragma unroll
            for (int r = 0; r < 4; r++) {
                int m = fa * 16 + (lane >> 4) * 4 + r;
                if (co0 + wco + m < coutT) yp[(i64)m * 361] = acc[fa][fb][r];
            }
    }
}

// =============== f32 conv (for CIN=18 first conv + fallback) ===============
template<int CIN>
__global__ __launch_bounds__(256)
void convgemm_k(const float* __restrict__ X, const float* __restrict__ wt,
                float* __restrict__ Y, int wtW, int coW0, int coutT)
{
    constexpr int NCB = (CIN + 15) / 16;
    constexpr int NS  = 9 * NCB;
    __shared__ float Ws[2][16][128];
    __shared__ float Bs[2][16][128];
    const int tid  = threadIdx.x;
    const int col0 = blockIdx.x * 128;
    const int co0  = blockIdx.y * 128;
    const int tn = tid & 15;
    const int tm = (tid >> 4) & 15;
    const int kkS  = tid >> 5;
    const int cS0  = (tid & 31) * 4;

    int y_[4], x_[4];
    const float* Xb[4];
#pragma unroll
    for (int j = 0; j < 4; j++) {
        int colj = col0 + cS0 + j;
        int nj = colj / 361;
        int sj = colj - nj * 361;
        y_[j] = sj / 19;
        x_[j] = sj - y_[j] * 19;
        Xb[j] = X + ((i64)nj * CIN) * 361 + sj;
    }

    float4 wA, wB, bA, bB;

#define STAGE(S)                                                               \
    {                                                                          \
        const int tap_ = (S) / NCB, cb_ = ((S) % NCB) * 16;                    \
        const int ky_ = tap_ / 3, kx_ = tap_ - ky_ * 3;                        \
        const int doff_ = (ky_ - 1) * 19 + (kx_ - 1);                          \
        const int ci0_ = cb_ + kkS, ci1_ = ci0_ + 8;                           \
        const float* wr_ = wt + ((i64)(tap_ * CIN) + ci0_) * wtW               \
                              + coW0 + co0 + cS0;                              \
        const bool wok_ = (coW0 + co0 + cS0) < wtW;                            \
        wA = (wok_ && ci0_ < CIN) ? *(const float4*)wr_                        \
                                  : float4{0.f, 0.f, 0.f, 0.f};                \
        wB = (wok_ && ci1_ < CIN) ? *(const float4*)(wr_ + (i64)8 * wtW)       \
                                  : float4{0.f, 0.f, 0.f, 0.f};                \
        bool v0_ = (y_[0]+ky_>=1)&(y_[0]+ky_<=19)&(x_[0]+kx_>=1)&(x_[0]+kx_<=19); \
        bool v1_ = (y_[1]+ky_>=1)&(y_[1]+ky_<=19)&(x_[1]+kx_>=1)&(x_[1]+kx_<=19); \
        bool v2_ = (y_[2]+ky_>=1)&(y_[2]+ky_<=19)&(x_[2]+kx_>=1)&(x_[2]+kx_<=19); \
        bool v3_ = (y_[3]+ky_>=1)&(y_[3]+ky_<=19)&(x_[3]+kx_>=1)&(x_[3]+kx_<=19); \
        bA.x = (v0_ && ci0_ < CIN) ? Xb[0][(i64)ci0_ * 361 + doff_] : 0.f;     \
        bA.y = (v1_ && ci0_ < CIN) ? Xb[1][(i64)ci0_ * 361 + doff_] : 0.f;     \
        bA.z = (v2_ && ci0_ < CIN) ? Xb[2][(i64)ci0_ * 361 + doff_] : 0.f;     \
        bA.w = (v3_ && ci0_ < CIN) ? Xb[3][(i64)ci0_ * 361 + doff_] : 0.f;     \
        bB.x = (v0_ && ci1_ < CIN) ? Xb[0][(i64)ci1_ * 361 + doff_] : 0.f;     \
        bB.y = (v1_ && ci1_ < CIN) ? Xb[1][(i64)ci1_ * 361 + doff_] : 0.f;     \
        bB.z = (v2_ && ci1_ < CIN) ? Xb[2][(i64)ci1_ * 361 + doff_] : 0.f;     \
        bB.w = (v3_ && ci1_ < CIN) ? Xb[3][(i64)ci1_ * 361 + doff_] : 0.f;     \
    }

#define WRITE(BUF)                                                             \
    {                                                                          \
        *(float4*)&Ws[BUF][kkS    ][cS0] = wA;                                 \
        *(float4*)&Ws[BUF][kkS + 8][cS0] = wB;                                 \
        *(float4*)&Bs[BUF][kkS    ][cS0] = bA;                                 \
        *(float4*)&Bs[BUF][kkS + 8][cS0] = bB;                                 \
    }

    float acc[8][8];
#pragma unroll
    for (int i = 0; i < 8; i++)
#pragma unroll
        for (int j = 0; j < 8; j++) acc[i][j] = 0.f;

    STAGE(0)
    WRITE(0)
    int cur = 0;
    for (int s = 0; s < NS; s++) {
        __syncthreads();
        if (s + 1 < NS) STAGE(s + 1)
#pragma unroll
        for (int kk = 0; kk < 16; kk++) {
            const float4 w0 = *(const float4*)&Ws[cur][kk][tm * 4];
            const float4 w1 = *(const float4*)&Ws[cur][kk][tm * 4 + 64];
            const float4 b0 = *(const float4*)&Bs[cur][kk][tn * 4];
            const float4 b1 = *(const float4*)&Bs[cur][kk][tn * 4 + 64];
            float wv[8] = {w0.x, w0.y, w0.z, w0.w, w1.x, w1.y, w1.z, w1.w};
            float bv[8] = {b0.x, b0.y, b0.z, b0.w, b1.x, b1.y, b1.z, b1.w};
#pragma unroll
            for (int wi = 0; wi < 8; wi++)
#pragma unroll
                for (int bj = 0; bj < 8; bj++)
                    acc[wi][bj] = fmaf(wv[wi], bv[bj], acc[wi][bj]);
        }
        if (s + 1 < NS) WRITE(cur ^ 1)
        cur ^= 1;
    }
#undef STAGE
#undef WRITE

#pragma unroll
    for (int bj = 0; bj < 8; bj++) {
        int lc = (bj < 4) ? (tn * 4 + bj) : (64 + tn * 4 + bj - 4);
        int colT = col0 + lc;
        int nT = colT / 361;
        int sT = colT - nT * 361;
        float* yp = Y + ((i64)nT * coutT + co0) * 361 + sT;
#pragma unroll
        for (int wi = 0; wi < 8; wi++) {
            int co = (wi < 4) ? (tm * 4 + wi) : (64 + tm * 4 + wi - 4);
            if (co0 + co < coutT) yp[(i64)co * 361] = acc[wi][bj];
        }
    }
}

// =============== BN batch-stats -> scale/shift ===============
__global__ __launch_bounds__(256)
void bnstats_k(const float* __restrict__ x, const float* __restrict__ g,
               const float* __restrict__ b, float* __restrict__ scale,
               float* __restrict__ shift, int C)
{
    const int c = blockIdx.x;
    float s = 0.f, s2 = 0.f;
    for (int n = 0; n < 128; n++) {
        const float* p = x + ((i64)n * C + c) * 361;
        for (int i = threadIdx.x; i < 361; i += 256) {
            float v = p[i]; s += v; s2 += v * v;
        }
    }
    __shared__ float rs[4], rq[4];
    for (int o = 32; o > 0; o >>= 1) { s += __shfl_down(s, o); s2 += __shfl_down(s2, o); }
    int lane = threadIdx.x & 63, wid = threadIdx.x >> 6;
    if (lane == 0) { rs[wid] = s; rq[wid] = s2; }
    __syncthreads();
    if (threadIdx.x == 0) {
        float S = rs[0] + rs[1] + rs[2] + rs[3];
        float Q = rq[0] + rq[1] + rq[2] + rq[3];
        const float inv = 1.f / 46208.f;
        float m  = S * inv;
        float var = Q * inv - m * m;
        float sc = g[c] * rsqrtf(var + 1e-5f);
        scale[c] = sc;
        shift[c] = b[c] - m * sc;
    }
}

// =============== BN apply variants (ws-only) ===============
__global__ void bn_relu_k(float* __restrict__ x, const float* __restrict__ scale,
                          const float* __restrict__ shift, int C, int total)
{
    for (int i = blockIdx.x * blockDim.x + threadIdx.x; i < total; i += gridDim.x * blockDim.x) {
        int c = (i / 361) % C;
        float v = fmaf(x[i], scale[c], shift[c]);
        x[i] = v > 0.f ? v : 0.f;
    }
}

__global__ void bn_add_relu_full_k(float* __restrict__ xa, const float* __restrict__ xc,
                                   const float* __restrict__ scale, const float* __restrict__ shift,
                                   int C, int total)
{
    for (int i = blockIdx.x * blockDim.x + threadIdx.x; i < total; i += gridDim.x * blockDim.x) {
        int c = (i / 361) % C;
        float v = xa[i] + fmaf(xc[i], scale[c], shift[c]);
        xa[i] = v > 0.f ? v : 0.f;
    }
}

__global__ void bn_add_relu_slice_k(float* __restrict__ xa, const float* __restrict__ xc,
                                    const float* __restrict__ scale, const float* __restrict__ shift,
                                    int cbase, int total)
{
    for (int i = blockIdx.x * blockDim.x + threadIdx.x; i < total; i += gridDim.x * blockDim.x) {
        int s = i % 361;
        int t = i / 361;
        int ch = t % 64;
        int n = t / 64;
        i64 ai = ((i64)n * 256 + cbase + ch) * 361 + s;
        float v = xa[ai] + fmaf(xc[i], scale[ch], shift[ch]);
        xa[ai] = v > 0.f ? v : 0.f;
    }
}

__global__ void bn_tanh_ws_k(const float* __restrict__ x, const float* __restrict__ scale,
                             const float* __restrict__ shift, float* __restrict__ zf, int total)
{
    for (int i = blockIdx.x * blockDim.x + threadIdx.x; i < total; i += gridDim.x * blockDim.x) {
        int c = (i / 361) & 31;
        zf[i] = tanhf(fmaf(x[i], scale[c], shift[c]));
    }
}

// =============== codebook prep ===============
__global__ void prep_k(const float* __restrict__ E0, const float* __restrict__ E1,
                       const float* __restrict__ E2,
                       float* __restrict__ ee0, float* __restrict__ ee1, float* __restrict__ ee2,
                       float* __restrict__ cm0, float* __restrict__ cm1, float* __restrict__ cm2)
{
    int t = threadIdx.x;
    if (blockIdx.x == 0) {
        float s = 0.f; const float* e = E0 + (i64)t * 32;
        for (int d = 0; d < 32; d++) s += e[d] * e[d];
        ee0[t] = s;
    } else if (blockIdx.x == 1) {
        float s = 0.f; const float* e = E1 + (i64)t * 64;
        for (int d = 0; d < 64; d++) s += e[d] * e[d];
        ee1[t] = s;
    } else if (blockIdx.x == 2) {
        float s = 0.f; const float* e = E2 + (i64)t * 64;
        for (int d = 0; d < 64; d++) s += e[d] * e[d];
        ee2[t] = s;
    } else {
        if (t < 32) {
            float s = 0.f; for (int k = 0; k < 512; k++) s += E0[k * 32 + t];
            cm0[t] = s * (1.f / 512.f);
        } else if (t >= 64 && t < 128) {
            int d = t - 64; float s = 0.f; for (int k = 0; k < 512; k++) s += E1[k * 64 + d];
            cm1[d] = s * (1.f / 512.f);
        } else if (t >= 128 && t < 192) {
            int d = t - 128; float s = 0.f; for (int k = 0; k < 512; k++) s += E2[k * 64 + d];
            cm2[d] = s * (1.f / 512.f);
        }
    }
}

// =============== VQ kernels ===============
__global__ __launch_bounds__(256)
void vq0_k(const float* __restrict__ z, const float* __restrict__ E,
           const float* __restrict__ ee, float* __restrict__ zqf, int* __restrict__ ki)
{
    __shared__ float Es[256 * 32];
    int row = blockIdx.x * 256 + threadIdx.x;
    const bool live = row < 46208;
    const float* zp = z + (i64)(live ? row : 0) * 32;
    float zv[32]; float zz = 0.f;
#pragma unroll
    for (int d = 0; d < 32; d++) { float v = zp[d]; zv[d] = v; zz += v * v; }
    float best = 3.4e38f; int bk = 0;
    for (int h = 0; h < 2; h++) {
        __syncthreads();
        for (int i = threadIdx.x; i < 256 * 32; i += 256) Es[i] = E[h * 8192 + i];
        __syncthreads();
        for (int k = 0; k < 256; k++) {
            const float* e = Es + k * 32;
            float dot = 0.f;
#pragma unroll
            for (int d = 0; d < 32; d++) dot = fmaf(zv[d], e[d], dot);
            float dist = (zz + ee[h * 256 + k]) - 2.f * dot;
            if (dist < best) { best = dist; bk = h * 256 + k; }
        }
    }
    if (live) {
        ki[row] = bk;
        const float* eb = E + (i64)bk * 32;
#pragma unroll
        for (int d = 0; d < 32; d++) zqf[(i64)row * 32 + d] = eb[d];
    }
}

__global__ __launch_bounds__(256)
void vq64_k(const float* __restrict__ z, const float* __restrict__ E,
            const float* __restrict__ ee, float* __restrict__ zqf, int* __restrict__ ki)
{
    __shared__ float Es[128 * 64];
    int row = blockIdx.x * 256 + threadIdx.x;
    const float* zp = z + (i64)row * 64;
    float zv[64]; float zz = 0.f;
#pragma unroll
    for (int d = 0; d < 64; d++) { float v = zp[d]; zv[d] = v; zz += v * v; }
    float best = 3.4e38f; int bk = 0;
    for (int h = 0; h < 4; h++) {
        __syncthreads();
        for (int i = threadIdx.x; i < 128 * 64; i += 256) Es[i] = E[(i64)h * 8192 + i];
        __syncthreads();
        for (int k = 0; k < 128; k++) {
            const float* e = Es + k * 64;
            float dot = 0.f;
#pragma unroll
            for (int d = 0; d < 64; d++) dot = fmaf(zv[d], e[d], dot);
            float dist = (zz + ee[h * 128 + k]) - 2.f * dot;
            if (dist < best) { best = dist; bk = h * 128 + k; }
        }
    }
    ki[row] = bk;
    const float* eb = E + (i64)bk * 64;
#pragma unroll
    for (int d = 0; d < 64; d++) zqf[(i64)row * 64 + d] = eb[d];
}

// =============== split-K GEMM ===============
__global__ __launch_bounds__(256)
void gemm_part_k(const float* __restrict__ A, const float* __restrict__ W,
                 float* __restrict__ part, int K, int N, int kchunk)
{
    __shared__ float As[128][17];
    __shared__ float Ws[16][64];
    const int n0 = blockIdx.x * 64;
    const int ks = blockIdx.y;
    const int kb0  = ks * kchunk;
    const int kend = min(K, kb0 + kchunk);
    const int tid = threadIdx.x;
    const int tn = tid & 15, tm = tid >> 4;
    float acc[8][4];
#pragma unroll
    for (int i = 0; i < 8; i++)
#pragma unroll
        for (int j = 0; j < 4; j++) acc[i][j] = 0.f;

    for (int kb = kb0; kb < kend; kb += 16) {
        __syncthreads();
        for (int i = tid; i < 2048; i += 256) {
            int m = i >> 4, kk = i & 15;
            int k = kb + kk;
            As[m][kk] = (k < kend) ? A[(i64)m * K + k] : 0.f;
        }
        for (int i = tid; i < 1024; i += 256) {
            int kk = i >> 6, nl = i & 63;
            int k = kb + kk, n = n0 + nl;
            Ws[kk][nl] = (k < kend && n < N) ? W[(i64)k * N + n] : 0.f;
        }
        __syncthreads();
#pragma unroll
        for (int kk = 0; kk < 16; kk++) {
            float av[8], wv[4];
#pragma unroll
            for (int i = 0; i < 8; i++) av[i] = As[tm * 8 + i][kk];
#pragma unroll
            for (int j = 0; j < 4; j++) wv[j] = Ws[kk][tn * 4 + j];
#pragma unroll
            for (int i = 0; i < 8; i++)
#pragma unroll
                for (int j = 0; j < 4; j++) acc[i][j] = fmaf(av[i], wv[j], acc[i][j]);
        }
    }
#pragma unroll
    for (int i = 0; i < 8; i++) {
        int m = tm * 8 + i;
#pragma unroll
        for (int j = 0; j < 4; j++) {
            int n = n0 + tn * 4 + j;
            if (n < N) part[((i64)ks * 128 + m) * N + n] = acc[i][j];
        }
    }
}

__global__ void combine_k(const float* __restrict__ part, const float* __restrict__ bias,
                          float* __restrict__ of, int MN, int N, int ksplit, int act)
{
    for (int i = blockIdx.x * blockDim.x + threadIdx.x; i < MN; i += gridDim.x * blockDim.x) {
        float s = 0.f;
        for (int t = 0; t < ksplit; t++) s += part[(i64)t * MN + i];
        s += bias[i % N];
        if (act == 1) s = s > 0.f ? s : 0.f;
        else if (act == 2) s = tanhf(s);
        of[i] = s;
    }
}

__global__ void blend_k(const float* __restrict__ q, const float* __restrict__ d,
                        const float* __restrict__ hu, int col, float* __restrict__ o,
                        int per_b, int total)
{
    for (int i = blockIdx.x * blockDim.x + threadIdx.x; i < total; i += gridDim.x * blockDim.x) {
        float u = hu[(i / per_b) * 2 + col];
        o[i] = u * q[i] + (1.f - u) * d[i];
    }
}

__global__ __launch_bounds__(256)
void value_k(const float* __restrict__ x, const float* __restrict__ w,
             const float* __restrict__ b, float* __restrict__ valf)
{
    int m = blockIdx.x;
    float s = 0.f;
    const float* xp = x + (i64)m * 11552;
    for (int k = threadIdx.x; k < 11552; k += 256) s = fmaf(xp[k], w[k], s);
    for (int o = 32; o > 0; o >>= 1) s += __shfl_down(s, o);
    __shared__ float r[4];
    int lane = threadIdx.x & 63, wid = threadIdx.x >> 6;
    if (lane == 0) r[wid] = s;
    __syncthreads();
    if (threadIdx.x == 0)
        valf[m] = tanhf(r[0] + r[1] + r[2] + r[3] + b[0]);
}

// =============== emit phase (d_out is FLOAT32) ===============
__global__ void emit_f32_k(const float* __restrict__ src, float* __restrict__ out, i64 off, int n)
{
    for (int i = blockIdx.x * blockDim.x + threadIdx.x; i < n; i += gridDim.x * blockDim.x)
        out[off + i] = src[i];
}

__global__ void emit_k_k(const int* __restrict__ ki, float* __restrict__ out, i64 off, int n)
{
    for (int i = blockIdx.x * blockDim.x + threadIdx.x; i < n; i += gridDim.x * blockDim.x)
        out[off + i] = (float)ki[i];
}

__global__ void emit_em_k(const float* __restrict__ cm, float* __restrict__ out, i64 off,
                          int D, int SPL, int total)
{
    for (int i = blockIdx.x * blockDim.x + threadIdx.x; i < total; i += gridDim.x * blockDim.x) {
        int c = (i / SPL) % D;
        out[off + i] = cm[c];
    }
}

// =============== guard markers ===============
__global__ void marker_k(float* __restrict__ out, int code)
{
    if (threadIdx.x < 64) out[threadIdx.x] = 3000.f + 100.f * code;
}

__global__ void sentinel_k(float* __restrict__ out)
{
    if (threadIdx.x < 128) out[OUT_VALUE + threadIdx.x] = 2000.0f;
}

// ===================== host launch =====================
extern "C" void kernel_launch(void* const* d_in, const int* in_sizes, int n_in,
                              void* d_out, int out_size, void* d_ws, size_t ws_size,
                              hipStream_t stream)
{
    float* out = (float*)d_out;

    int bad = -1;
    if (out_size != (int)OUT_TOTAL) bad = 0;
    else if (n_in != 41) bad = 1;
    else if (in_sizes[0] != 128 * 18 * 361) bad = 2;
    else if (in_sizes[21] != 11552 * 256) bad = 3;
    if (bad >= 0) { marker_k<<<1, 64, 0, stream>>>(out, bad); return; }

    const float* obs   = (const float*)d_in[0];
    const float* hier  = (const float*)d_in[1];
    const float* c0w   = (const float*)d_in[2];
    const float* bn0g  = (const float*)d_in[4];
    const float* bn0b  = (const float*)d_in[5];
    const float* rb1w  = (const float*)d_in[6];
    const float* rbn1g = (const float*)d_in[8];
    const float* rbn1b = (const float*)d_in[9];
    const float* rb2w  = (const float*)d_in[10];
    const float* rbn2g = (const float*)d_in[12];
    const float* rbn2b = (const float*)d_in[13];
    const float* c2w   = (const float*)d_in[14];
    const float* bn2g  = (const float*)d_in[16];
    const float* bn2b  = (const float*)d_in[17];
    const float* E0    = (const float*)d_in[18];
    const float* E1    = (const float*)d_in[19];
    const float* E2    = (const float*)d_in[20];
    const float* fc1w  = (const float*)d_in[21]; const float* fc1b  = (const float*)d_in[22];
    const float* fc2w  = (const float*)d_in[23]; const float* fc2b  = (const float*)d_in[24];
    const float* h2fw  = (const float*)d_in[25]; const float* h2fb  = (const float*)d_in[26];
    const float* h2f2w = (const float*)d_in[27]; const float* h2f2b = (const float*)d_in[28];
    const float* h2f3w = (const float*)d_in[29]; const float* h2f3b = (const float*)d_in[30];
    const float* h2f4w = (const float*)d_in[31]; const float* h2f4b = (const float*)d_in[32];
    const float* h1f3w = (const float*)d_in[33]; const float* h1f3b = (const float*)d_in[34];
    const float* h1f4w = (const float*)d_in[35]; const float* h1f4b = (const float*)d_in[36];
    const float* polw  = (const float*)d_in[37]; const float* polb  = (const float*)d_in[38];
    const float* valw  = (const float*)d_in[39]; const float* valb  = (const float*)d_in[40];

    float* wsf = (float*)d_ws;

    const size_t NEED_A = (size_t)36732928 * 4;
    const size_t NEED_C = (size_t)27860992 * 4;
    if (ws_size < NEED_C) {
        sentinel_k<<<1, 128, 0, stream>>>(out);
        return;
    }
    const bool fullC = (ws_size >= NEED_A);

    float* scale = wsf + 0;        float* shift = wsf + 256;
    float* ee0 = wsf + 512;        float* ee1 = wsf + 1024;   float* ee2 = wsf + 1536;
    float* cm0 = wsf + 2048;       float* cm1 = wsf + 2112;   float* cm2 = wsf + 2176;
    int*   k0i = (int*)(wsf + 4096);
    int*   k1i = (int*)(wsf + 50304);
    int*   k2i = (int*)(wsf + 51328);
    float* h1a  = wsf + 53248;
    float* ze1f = wsf + 86016;
    float* zq1f = wsf + 151552;
    float* h2a  = wsf + 217088;
    float* ze2f = wsf + 233472;
    float* zq2f = wsf + 299008;
    float* h2b  = wsf + 364544;
    float* decf = wsf + 380928;
    float* x1f  = wsf + 446464;
    float* h1b  = wsf + 512000;
    float* polf = wsf + 544768;
    float* valf = wsf + 591104;

    float* A    = wsf + 655360;
    float* B    = wsf + 12484608;
    float* C    = wsf + 24313856;
    float* WT   = fullC ? (wsf + 36143104) : (wsf + 27271168);
    float* ze0f = A;
    float* zq0f = wsf + 655360 + 1572864;
    float* dec0 = wsf + 655360 + 3145728;
    float* xf   = wsf + 655360 + 4718592;
    float* part = B;

    // bf16 split weights live in d_out (dead until the emit phase)
    short* WT4 = (short*)d_out;

    const int TOT256 = 128 * 256 * 361;
    const int TOT32  = 128 * 32 * 361;
    const int TOT64  = 128 * 64 * 361;

    prep_k<<<4, 512, 0, stream>>>(E0, E1, E2, ee0, ee1, ee2, cm0, cm1, cm2);

    // ---- trunk ----
    wtr_k<<<64, 256, 0, stream>>>(c0w, WT, 256, 18);
    convgemm_k<18><<<dim3(361, 2), 256, 0, stream>>>(obs, WT, A, 256, 0, 256);
    bnstats_k<<<256, 256, 0, stream>>>(A, bn0g, bn0b, scale, shift, 256);
    bn_relu_k<<<1024, 256, 0, stream>>>(A, scale, shift, 256, TOT256);

    for (int i = 0; i < 3; i++) {
        if (fullC) {
            wtr4_k<<<1024, 256, 0, stream>>>(rb1w + (i64)i * 589824, WT4, 256, 256);
            convmfma_k<256><<<dim3(361, 2), 256, 0, stream>>>(A, WT4, B, 256);
        } else {
            wtr_k<<<576, 256, 0, stream>>>(rb1w + (i64)i * 589824, WT, 256, 256);
            convgemm_k<256><<<dim3(361, 2), 256, 0, stream>>>(A, WT, B, 256, 0, 256);
        }
        bnstats_k<<<256, 256, 0, stream>>>(B, rbn1g + i * 256, rbn1b + i * 256, scale, shift, 256);
        bn_relu_k<<<1024, 256, 0, stream>>>(B, scale, shift, 256, TOT256);
        if (fullC) {
            wtr4_k<<<1024, 256, 0, stream>>>(rb2w + (i64)i * 589824, WT4, 256, 256);
            convmfma_k<256><<<dim3(361, 2), 256, 0, stream>>>(B, WT4, C, 256);
            bnstats_k<<<256, 256, 0, stream>>>(C, rbn2g + i * 256, rbn2b + i * 256, scale, shift, 256);
            bn_add_relu_full_k<<<1024, 256, 0, stream>>>(A, C, scale, shift, 256, TOT256);
        } else {
            wtr_k<<<576, 256, 0, stream>>>(rb2w + (i64)i * 589824, WT, 256, 256);
            for (int c = 0; c < 4; c++) {
                convgemm_k<256><<<dim3(361, 1), 256, 0, stream>>>(B, WT, C, 256, c * 64, 64);
                bnstats_k<<<64, 256, 0, stream>>>(C, rbn2g + i * 256 + c * 64,
                                                  rbn2b + i * 256 + c * 64, scale, shift, 64);
                bn_add_relu_slice_k<<<1024, 256, 0, stream>>>(A, C, scale, shift, c * 64, TOT64);
            }
        }
    }

    if (fullC) {
        wtr4_k<<<1024, 256, 0, stream>>>(c2w, WT4, 256, 32);
        convmfma_k<256><<<dim3(361, 1), 256, 0, stream>>>(A, WT4, C, 32);
    } else {
        wtr_k<<<72, 256, 0, stream>>>(c2w, WT, 32, 256);
        convgemm_k<256><<<dim3(361, 1), 256, 0, stream>>>(A, WT, C, 32, 0, 32);
    }
    bnstats_k<<<32, 256, 0, stream>>>(C, bn2g, bn2b, scale, shift, 32);
    bn_tanh_ws_k<<<1024, 256, 0, stream>>>(C, scale, shift, ze0f, TOT32);

    vq0_k<<<181, 256, 0, stream>>>(ze0f, E0, ee0, zq0f, k0i);

    gemm_part_k<<<dim3(4, 32), 256, 0, stream>>>(ze0f, fc1w, part, 11552, 256, 361);
    combine_k<<<128, 256, 0, stream>>>(part, fc1b, h1a, 128 * 256, 256, 32, 1);
    gemm_part_k<<<dim3(8, 4), 256, 0, stream>>>(h1a, fc2w, part, 256, 512, 64);
    combine_k<<<256, 256, 0, stream>>>(part, fc2b, ze1f, 128 * 512, 512, 4, 2);
    vq64_k<<<4, 256, 0, stream>>>(ze1f, E1, ee1, zq1f, k1i);

    gemm_part_k<<<dim3(2, 8), 256, 0, stream>>>(ze1f, h2fw, part, 512, 128, 64);
    combine_k<<<64, 256, 0, stream>>>(part, h2fb, h2a, 128 * 128, 128, 8, 1);
    gemm_part_k<<<dim3(8, 2), 256, 0, stream>>>(h2a, h2f2w, part, 128, 512, 64);
    combine_k<<<256, 256, 0, stream>>>(part, h2f2b, ze2f, 128 * 512, 512, 2, 2);
    vq64_k<<<4, 256, 0, stream>>>(ze2f, E2, ee2, zq2f, k2i);

    gemm_part_k<<<dim3(2, 8), 256, 0, stream>>>(zq2f, h2f3w, part, 512, 128, 64);
    combine_k<<<64, 256, 0, stream>>>(part, h2f3b, h2b, 128 * 128, 128, 8, 1);
    gemm_part_k<<<dim3(8, 2), 256, 0, stream>>>(h2b, h2f4w, part, 128, 512, 64);
    combine_k<<<256, 256, 0, stream>>>(part, h2f4b, decf, 128 * 512, 512, 2, 2);
    blend_k<<<256, 256, 0, stream>>>(zq1f, decf, hier, 1, x1f, 512, 65536);

    gemm_part_k<<<dim3(4, 8), 256, 0, stream>>>(x1f, h1f3w, part, 512, 256, 64);
    combine_k<<<128, 256, 0, stream>>>(part, h1f3b, h1b, 128 * 256, 256, 8, 1);
    gemm_part_k<<<dim3(181, 2), 256, 0, stream>>>(h1b, h1f4w, part, 256, 11552, 128);
    combine_k<<<1024, 256, 0, stream>>>(part, h1f4b, dec0, TOT32, 11552, 2, 2);
    blend_k<<<1024, 256, 0, stream>>>(zq0f, dec0, hier, 0, xf, 11552, TOT32);

    gemm_part_k<<<dim3(6, 16), 256, 0, stream>>>(xf, polw, part, 11552, 362, 722);
    combine_k<<<256, 256, 0, stream>>>(part, polb, polf, 128 * 362, 362, 16, 0);
    value_k<<<128, 256, 0, stream>>>(xf, valw, valb, valf);

    // ---- emit phase (overwrites WT4 region; sole d_out writers from here) ----
    emit_f32_k<<<128, 256, 0, stream>>>(polf, out, OUT_POLICY, 46336);
    emit_f32_k<<<1, 128, 0, stream>>>(valf, out, OUT_VALUE, 128);
    emit_f32_k<<<1024, 256, 0, stream>>>(ze0f, out, OUT_ZE0, TOT32);
    emit_f32_k<<<256, 256, 0, stream>>>(ze1f, out, OUT_ZE1, 65536);
    emit_f32_k<<<256, 256, 0, stream>>>(ze2f, out, OUT_ZE2, 65536);
    emit_f32_k<<<1024, 256, 0, stream>>>(zq0f, out, OUT_ZQ0, TOT32);
    emit_f32_k<<<256, 256, 0, stream>>>(zq1f, out, OUT_ZQ1, 65536);
    emit_f32_k<<<256, 256, 0, stream>>>(zq2f, out, OUT_ZQ2, 65536);
    emit_k_k<<<181, 256, 0, stream>>>(k0i, out, OUT_K0, 46208);
    emit_k_k<<<4, 256, 0, stream>>>(k1i, out, OUT_K1, 1024);
    emit_k_k<<<4, 256, 0, stream>>>(k2i, out, OUT_K2, 1024);
    emit_f32_k<<<1024, 256, 0, stream>>>(zq0f, out, OUT_ZQL0, TOT32);
    emit_f32_k<<<256, 256, 0, stream>>>(zq1f, out, OUT_ZQL1, 65536);
    emit_f32_k<<<256, 256, 0, stream>>>(zq2f, out, OUT_ZQL2, 65536);
    emit_em_k<<<1024, 256, 0, stream>>>(cm0, out, OUT_EM0, 32, 361, TOT32);
    emit_em_k<<<256, 256, 0, stream>>>(cm1, out, OUT_EM1, 64, 8, 65536);
    emit_em_k<<<256, 256, 0, stream>>>(cm2, out, OUT_EM2, 64, 8, 65536);
}